// Round 3
// baseline (941.755 us; speedup 1.0000x reference)
//
#include <hip/hip_runtime.h>
#include <cmath>

#define LSEQ 2048
#define NBATCH 8

typedef __attribute__((ext_vector_type(8))) short short8;
typedef __attribute__((ext_vector_type(4))) float f32x4;

__device__ __forceinline__ float silu_f(float x) {
    return x * __builtin_amdgcn_rcpf(1.0f + __expf(-x));
}
__device__ __forceinline__ float softplus_f(float x) {
    return fmaxf(x, 0.0f) + __logf(1.0f + __expf(-fabsf(x)));
}
__device__ __forceinline__ unsigned short f2bf(float f) {   // RNE fp32->bf16
    unsigned int u = __float_as_uint(f);
    u += 0x7FFFu + ((u >> 16) & 1u);
    return (unsigned short)(u >> 16);
}
__device__ __forceinline__ float bf2f(unsigned short h) {
    return __uint_as_float(((unsigned int)h) << 16);
}
__device__ __forceinline__ void gload_lds16(const void* g, void* l) {
    __builtin_amdgcn_global_load_lds((const __attribute__((address_space(1))) void*)g,
                                     (__attribute__((address_space(3))) void*)l, 16, 0, 0);
}

#if defined(__has_builtin)
#if __has_builtin(__builtin_amdgcn_exp2f)
#define EXP2F(x) __builtin_amdgcn_exp2f(x)
#endif
#endif
#ifndef EXP2F
#define EXP2F(x) __expf((x) * 0.69314718055994531f)
#endif

// fwd/bwd operand pairs; blockIdx.z selects direction
struct GemmPair {
    const unsigned short* A[2];
    const unsigned short* A2[2];   // DUAL second A (second K-half, row-reversed)
    const unsigned short* W[2];
    const float* bias[2];
    void* C[2];
    unsigned short* aux[2];
};

// ---------------------------------------------------------------------------
// bf16 MFMA GEMM (NT), r4-proven config: BK=32, scalar epilogue.
// ---------------------------------------------------------------------------
template<int WGM, int WGN, int OMODE, int DK, int XTRA>
__global__ __launch_bounds__(WGM* WGN * 64) void gemm_mfma(GemmPair gp, int lda, int ldw,
                                                           int ldc, int K)
{
    constexpr int NW = WGM * WGN;
    constexpr int TM = WGM * 64, TN = WGN * 64;
    __shared__ unsigned short As[TM * 32];
    __shared__ unsigned short Bs[TN * 32];
    const int dir = blockIdx.z;
    const unsigned short* A  = gp.A[dir];
    const unsigned short* A2 = gp.A2[dir];
    const unsigned short* W  = gp.W[dir];
    const float* bias        = gp.bias[dir];
    void* Cout               = gp.C[dir];
    unsigned short* aux      = gp.aux[dir];

    const int tid = threadIdx.x;
    const int wave = tid >> 6, lane = tid & 63;
    const int wm = wave / WGN, wn = wave % WGN;
    const int m0 = blockIdx.x * TM, n0 = blockIdx.y * TN;
    const int l15 = lane & 15, l4 = lane >> 4;
    const int srow = lane >> 2, schunk = (lane & 3) * 8;

    f32x4 acc[4][4] = {};

    for (int k0 = 0; k0 < K; k0 += 32) {
        __syncthreads();
        for (int s = wave; s < TM / 16; s += NW) {
            const int gr = m0 + s * 16 + srow;
            const unsigned short* g;
            if (DK != 0 && k0 >= DK)
                g = A2 + (size_t)(gr ^ (LSEQ - 1)) * lda + (k0 - DK) + schunk;
            else
                g = A + (size_t)gr * lda + k0 + schunk;
            gload_lds16(g, (char*)As + (size_t)s * 1024);
        }
        for (int s = wave; s < TN / 16; s += NW) {
            const int gr = n0 + s * 16 + srow;
            const unsigned short* g = W + (size_t)gr * ldw + k0 + schunk;
            gload_lds16(g, (char*)Bs + (size_t)s * 1024);
        }
        __syncthreads();
        short8 af[4], bfr[4];
#pragma unroll
        for (int mi = 0; mi < 4; ++mi)
            af[mi] = *(const short8*)&As[(wm * 64 + mi * 16 + l15) * 32 + l4 * 8];
#pragma unroll
        for (int ni = 0; ni < 4; ++ni)
            bfr[ni] = *(const short8*)&Bs[(wn * 64 + ni * 16 + l15) * 32 + l4 * 8];
#pragma unroll
        for (int mi = 0; mi < 4; ++mi)
#pragma unroll
            for (int ni = 0; ni < 4; ++ni)
                acc[mi][ni] = __builtin_amdgcn_mfma_f32_16x16x32_bf16(af[mi], bfr[ni], acc[mi][ni], 0, 0, 0);
    }

#pragma unroll
    for (int mi = 0; mi < 4; ++mi)
#pragma unroll
        for (int ni = 0; ni < 4; ++ni)
#pragma unroll
            for (int r = 0; r < 4; ++r) {
                const int row = m0 + wm * 64 + mi * 16 + l4 * 4 + r;
                const int col = n0 + wn * 64 + ni * 16 + l15;
                float v = acc[mi][ni][r];
                if (bias) v += bias[col];
                if (OMODE & 1) ((unsigned short*)Cout)[(size_t)row * ldc + col] = f2bf(v);
                else           ((float*)Cout)[(size_t)row * ldc + col] = v;
                if (XTRA) { if (col < 32) aux[(size_t)row * 32 + col] = f2bf(v); }
            }
}

// ---------------------------------------------------------------------------
// Combined weight for fused out-proj+final (proven r7: identical absmax):
// ---------------------------------------------------------------------------
__global__ __launch_bounds__(256) void combine_k(
    const float* __restrict__ lin_w, const float* __restrict__ owf,
    const float* __restrict__ owb, unsigned short* __restrict__ Wcomb)
{
    const int dir = blockIdx.z;
    const float* ow = dir ? owb : owf;
    const int lane = threadIdx.x & 63;
    const int wave = threadIdx.x >> 6;
    const int n = blockIdx.y * 4 + wave;          // 0..511
    const int d = blockIdx.x * 256 + lane * 4;    // 0..1023
    float4 acc = {0.f, 0.f, 0.f, 0.f};
    const float* lrow = lin_w + (size_t)n * 1024 + dir * 512;
    for (int j = 0; j < 512; ++j) {
        const float s = lrow[j];
        const float4 v = *(const float4*)&ow[(size_t)j * 1024 + d];
        acc.x = fmaf(s, v.x, acc.x); acc.y = fmaf(s, v.y, acc.y);
        acc.z = fmaf(s, v.z, acc.z); acc.w = fmaf(s, v.w, acc.w);
    }
    ushort4 o;
    o.x = f2bf(acc.x); o.y = f2bf(acc.y); o.z = f2bf(acc.z); o.w = f2bf(acc.w);
    *(ushort4*)&Wcomb[(size_t)n * 2048 + dir * 1024 + d] = o;
}

// ---------------------------------------------------------------------------
// fp32 -> bf16 conversion: 6 weight segments, one launch.
// ---------------------------------------------------------------------------
struct CvtArgs { const float* s[6]; unsigned short* d[6]; int n[6]; };
__global__ __launch_bounds__(256) void cvt_k(CvtArgs a)
{
    const int sid = blockIdx.y;
    const float* s = a.s[sid];
    unsigned short* d = a.d[sid];
    const int n4 = a.n[sid] >> 2;
    for (int i = blockIdx.x * 256 + threadIdx.x; i < n4; i += gridDim.x * 256) {
        const float4 v = ((const float4*)s)[i];
        ushort4 o; o.x = f2bf(v.x); o.y = f2bf(v.y); o.z = f2bf(v.z); o.w = f2bf(v.w);
        ((ushort4*)d)[i] = o;
    }
}
__global__ __launch_bounds__(256) void cvtx_k(const float* __restrict__ s,
                                              unsigned short* __restrict__ d, int n4)
{
    for (int i = blockIdx.x * 256 + threadIdx.x; i < n4; i += gridDim.x * 256) {
        const float4 v = ((const float4*)s)[i];
        ushort4 o; o.x = f2bf(v.x); o.y = f2bf(v.y); o.z = f2bf(v.z); o.w = f2bf(v.w);
        ((ushort4*)d)[i] = o;
    }
}

// A_log -> -exp(A_log)*log2(e) tables for both dirs (used by fix_k)
__global__ __launch_bounds__(256) void alprep_k(const float* __restrict__ af,
                                                const float* __restrict__ ab,
                                                float* __restrict__ of,
                                                float* __restrict__ ob)
{
    const int i = blockIdx.x * 256 + threadIdx.x;
    if (i < 16384) {
        of[i] = -expf(af[i]) * 1.4426950408889634f;
        ob[i] = -expf(ab[i]) * 1.4426950408889634f;
    }
}

// ---------------------------------------------------------------------------
// Causal depthwise conv(4) + bias + SiLU, both dirs.
// ---------------------------------------------------------------------------
__global__ __launch_bounds__(256) void conv_silu_k(
    const unsigned short* __restrict__ xz_f, const float* __restrict__ cw_f,
    const float* __restrict__ cb_f, unsigned short* __restrict__ xi_f,
    const unsigned short* __restrict__ xz_b, const float* __restrict__ cw_b,
    const float* __restrict__ cb_b, unsigned short* __restrict__ xi_b)
{
    const int dir = blockIdx.y;
    const unsigned short* xz = dir ? xz_b : xz_f;
    const float* cw = dir ? cw_b : cw_f;
    const float* cb = dir ? cb_b : cb_f;
    unsigned short* xi = dir ? xi_b : xi_f;

    const int bt = blockIdx.x;
    const int b = bt >> 11;
    const int t = bt & (LSEQ - 1);
    const int d = threadIdx.x << 2;

    float w[4][4];
#pragma unroll
    for (int i = 0; i < 4; ++i) {
        const float4 wr = *(const float4*)&cw[(d + i) * 4];
        w[i][0] = wr.x; w[i][1] = wr.y; w[i][2] = wr.z; w[i][3] = wr.w;
    }
    float4 acc = *(const float4*)&cb[d];
#pragma unroll
    for (int k = 0; k < 4; ++k) {
        const int row = dir ? (LSEQ - 1 - t) + 3 - k : t - 3 + k;
        if ((unsigned)row < (unsigned)LSEQ) {
            const ushort4 v = *(const ushort4*)&xz[(size_t)(b * LSEQ + row) * 2048 + d];
            acc.x += w[0][k] * bf2f(v.x); acc.y += w[1][k] * bf2f(v.y);
            acc.z += w[2][k] * bf2f(v.z); acc.w += w[3][k] * bf2f(v.w);
        }
    }
    ushort4 st;
    st.x = f2bf(silu_f(acc.x)); st.y = f2bf(silu_f(acc.y));
    st.z = f2bf(silu_f(acc.z)); st.w = f2bf(silu_f(acc.w));
    *(ushort4*)&xi[(size_t)(b * LSEQ + t) * 1024 + d] = st;
}

// ---------------------------------------------------------------------------
// Selective scan, seq-split P=2 version (round 3):
//  - blockIdx.y = b*2 + part; each block scans 1024 rows (16 chunks of 64).
//  - part 0: full scan + gated epilogue + h_end store (he).
//  - part 1: local scan from h=0; stores cumΔ (cumsum of dt) per (t,d) and
//    raw y + xi*Dp (f32, yd); gating+correction done by fix_k.
//  - LDS 39.3 KB -> 4 blocks/CU (vs 2); 2 barriers/chunk (epilogue reads
//    xi/z from registers; sy disjoint from staging arrays).
// ---------------------------------------------------------------------------
__device__ __forceinline__ float row_sum8(float x) {
    x += __int_as_float(__builtin_amdgcn_update_dpp(0, __float_as_int(x), 0xB1, 0xF, 0xF, true));  // quad xor1
    x += __int_as_float(__builtin_amdgcn_update_dpp(0, __float_as_int(x), 0x4E, 0xF, 0xF, true));  // quad xor2
    x += __int_as_float(__builtin_amdgcn_update_dpp(0, __float_as_int(x), 0x141, 0xF, 0xF, true)); // row_half_mirror
    return x;
}

struct ScanPair {
    const unsigned short* dblh[2];   // (rows x 32) bf16
    const unsigned short* dtw[2];    // (1024 x 32) bf16
    const float* dtb[2];             // (1024) f32
    unsigned short* xiy[2];          // (rows x 1024) bf16, in/out
    const float* dbl[2];             // (rows x 64) f32, B/C in cols 32..63
    const unsigned short* xz[2];     // (rows x 2048) bf16, z in cols 1024+
    const float* Al[2];
    const float* Dp[2];
    float* cumg[2];                  // (G*1024 x 1024) f32: part-1 cumsum(dt)
    float* yd[2];                    // (G*1024 x 1024) f32: part-1 y + xi*Dp
    float* he[2];                    // (G*1024 x 16) f32: part-0 h_end
};

__global__ __launch_bounds__(256, 4) void scan_k(ScanPair sp)
{
    __shared__ unsigned short sxi[64][40];       // [t][ch] raw bf16
    __shared__ float sdt[32][68], sdtx[32][68];  // [ch][t]
    __shared__ float sB2[8][140], sC2[8][140];   // [np][t*2+half]: {B_np, B_np+8}
    __shared__ float sy[32][68];                 // [ch][t]

    const int dir = blockIdx.z;
    const unsigned short* dblh = sp.dblh[dir];
    const unsigned short* dtw  = sp.dtw[dir];
    const float* dtb           = sp.dtb[dir];
    unsigned short* xiy        = sp.xiy[dir];
    const float* dbl           = sp.dbl[dir];
    const unsigned short* zz   = sp.xz[dir];
    const float* Al            = sp.Al[dir];
    const float* Dpp           = sp.Dp[dir];
    float* cumg                = sp.cumg[dir];
    float* ydp                 = sp.yd[dir];
    float* hep                 = sp.he[dir];

    const int by = blockIdx.y;
    const int b = by >> 1, part = by & 1;
    const int rbase = b * LSEQ + part * (LSEQ / 2);
    const int d0 = blockIdx.x << 5;
    const int tid = threadIdx.x;
    const int wave = tid >> 6, lane = tid & 63;
    const int l15 = lane & 15, l4 = lane >> 4;
    const int di = tid >> 3, np = tid & 7;     // inner-loop mapping
    const int lr = tid >> 2, lc = tid & 3;     // stage/epilogue mapping
    const bool lead = (np == 0);

    // A constants pre-scaled by log2(e) so exp2 needs no extra mul
    const float A0L = -expf(Al[(d0 + di) * 16 + np]) * 1.4426950408889634f;
    const float A1L = -expf(Al[(d0 + di) * 16 + np + 8]) * 1.4426950408889634f;

    // dt MFMA B-fragments: rows = the block's 32 channels (two 16-ch halves)
    const short8 dtwf0 = *(const short8*)&dtw[(size_t)(d0 + l15) * 32 + l4 * 8];
    const short8 dtwf1 = *(const short8*)&dtw[(size_t)(d0 + 16 + l15) * 32 + l4 * 8];
    const float dtb0 = dtb[d0 + l15], dtb1 = dtb[d0 + 16 + l15];

    float dpv[8];
#pragma unroll
    for (int i = 0; i < 8; ++i) dpv[i] = Dpp[d0 + lc * 8 + i];

    ushort4 pxi0, pxi1;
    float4 pB, pC;
    short8 pA;
    auto issue_loads = [&](int c) {
        const size_t r = (size_t)rbase + c * 64 + lr;
        pxi0 = *(const ushort4*)&xiy[r * 1024 + d0 + lc * 8];
        pxi1 = *(const ushort4*)&xiy[r * 1024 + d0 + lc * 8 + 4];
        pB   = *(const float4*)&dbl[r * 64 + 32 + lc * 4];
        pC   = *(const float4*)&dbl[r * 64 + 48 + lc * 4];
        // dt MFMA A-fragment: rows = this wave's 16 timesteps of the chunk
        pA   = *(const short8*)&dblh[(size_t)(rbase + c * 64 + wave * 16 + l15) * 32 + l4 * 8];
    };
    issue_loads(0);

    constexpr int NT = (LSEQ / 2) / 64;   // 16 chunks per partition
    float h0 = 0.0f, h1 = 0.0f, cum = 0.0f;
    for (int c = 0; c < NT; ++c) {
        const int t0 = c * 64;
        // ---- stage xi raw bf16 [t][ch] and B/C pairs ----
        *(ushort4*)&sxi[lr][lc * 8]     = pxi0;
        *(ushort4*)&sxi[lr][lc * 8 + 4] = pxi1;
        {
            const float bv[4] = {pB.x, pB.y, pB.z, pB.w};
            const float cv[4] = {pC.x, pC.y, pC.z, pC.w};
#pragma unroll
            for (int i = 0; i < 4; ++i) {
                const int n = lc * 4 + i;
                sB2[n & 7][lr * 2 + (n >> 3)] = bv[i];
                sC2[n & 7][lr * 2 + (n >> 3)] = cv[i];
            }
        }
        // ---- dt phase: MFMA -> softplus -> sdt, and dtx = dt*xi -> sdtx ----
        // NOTE: reads sxi written above by this thread's wave-mates; the
        // lgkm ordering is NOT guaranteed pre-barrier across waves, but the
        // sxi rows read here (tq..tq+3) were written by threads lr=tq..tq+3
        // which may be in other waves -> must come after a barrier.
        __syncthreads();   // barC-pre: stage visible to all
        {
            f32x4 z4 = {0.f, 0.f, 0.f, 0.f};
            f32x4 dacc0 = __builtin_amdgcn_mfma_f32_16x16x32_bf16(pA, dtwf0, z4, 0, 0, 0);
            f32x4 dacc1 = __builtin_amdgcn_mfma_f32_16x16x32_bf16(pA, dtwf1, z4, 0, 0, 0);
            const int tq = wave * 16 + l4 * 4;
            float4 xi0, xi1;
            xi0.x = bf2f(sxi[tq + 0][l15]);      xi0.y = bf2f(sxi[tq + 1][l15]);
            xi0.z = bf2f(sxi[tq + 2][l15]);      xi0.w = bf2f(sxi[tq + 3][l15]);
            xi1.x = bf2f(sxi[tq + 0][16 + l15]); xi1.y = bf2f(sxi[tq + 1][16 + l15]);
            xi1.z = bf2f(sxi[tq + 2][16 + l15]); xi1.w = bf2f(sxi[tq + 3][16 + l15]);
            float4 dv0, dv1, dx0, dx1;
            dv0.x = softplus_f(dacc0[0] + dtb0); dv0.y = softplus_f(dacc0[1] + dtb0);
            dv0.z = softplus_f(dacc0[2] + dtb0); dv0.w = softplus_f(dacc0[3] + dtb0);
            dv1.x = softplus_f(dacc1[0] + dtb1); dv1.y = softplus_f(dacc1[1] + dtb1);
            dv1.z = softplus_f(dacc1[2] + dtb1); dv1.w = softplus_f(dacc1[3] + dtb1);
            dx0.x = dv0.x * xi0.x; dx0.y = dv0.y * xi0.y;
            dx0.z = dv0.z * xi0.z; dx0.w = dv0.w * xi0.w;
            dx1.x = dv1.x * xi1.x; dx1.y = dv1.y * xi1.y;
            dx1.z = dv1.z * xi1.z; dx1.w = dv1.w * xi1.w;
            *(float4*)&sdt[l15][tq]       = dv0;
            *(float4*)&sdt[16 + l15][tq]  = dv1;
            *(float4*)&sdtx[l15][tq]      = dx0;
            *(float4*)&sdtx[16 + l15][tq] = dx1;
        }
        const ushort4 oxi0 = pxi0, oxi1 = pxi1;
        ushort4 pz0 = {}, pz1 = {};
        if (part == 0) {
            const int tg = t0 + lr;
            const int tz = dir ? (LSEQ - 1 - tg) : tg;
            pz0 = *(const ushort4*)&zz[((size_t)b * LSEQ + tz) * 2048 + 1024 + d0 + lc * 8];
            pz1 = *(const ushort4*)&zz[((size_t)b * LSEQ + tz) * 2048 + 1024 + d0 + lc * 8 + 4];
        }
        if (c + 1 < NT) issue_loads(c + 1);
        __syncthreads();   // barC: sdt/sdtx visible, inner may start
        // ---- inner scan: 64 timesteps, 2 states per thread ----
#pragma unroll 4
        for (int tt = 0; tt < 64; tt += 4) {
            const float4 d4 = *(const float4*)&sdt[di][tt];
            const float4 u4 = *(const float4*)&sdtx[di][tt];
            const float4 bA = *(const float4*)&sB2[np][tt * 2];
            const float4 bB = *(const float4*)&sB2[np][tt * 2 + 4];
            const float4 cA = *(const float4*)&sC2[np][tt * 2];
            const float4 cB = *(const float4*)&sC2[np][tt * 2 + 4];
            float4 ppv;
            h0 = fmaf(EXP2F(d4.x * A0L), h0, u4.x * bA.x);
            h1 = fmaf(EXP2F(d4.x * A1L), h1, u4.x * bA.y);
            ppv.x = row_sum8(fmaf(h1, cA.y, h0 * cA.x));
            h0 = fmaf(EXP2F(d4.y * A0L), h0, u4.y * bA.z);
            h1 = fmaf(EXP2F(d4.y * A1L), h1, u4.y * bA.w);
            ppv.y = row_sum8(fmaf(h1, cA.w, h0 * cA.z));
            h0 = fmaf(EXP2F(d4.z * A0L), h0, u4.z * bB.x);
            h1 = fmaf(EXP2F(d4.z * A1L), h1, u4.z * bB.y);
            ppv.z = row_sum8(fmaf(h1, cB.y, h0 * cB.x));
            h0 = fmaf(EXP2F(d4.w * A0L), h0, u4.w * bB.z);
            h1 = fmaf(EXP2F(d4.w * A1L), h1, u4.w * bB.w);
            ppv.w = row_sum8(fmaf(h1, cB.w, h0 * cB.z));
            if (part) {
                const float c0 = cum + d4.x, c1 = c0 + d4.y;
                const float c2 = c1 + d4.z, c3 = c2 + d4.w;
                cum = c3;
                if (lead) {
                    float* cg = &cumg[(size_t)(b * (LSEQ / 2) + t0 + tt) * 1024 + d0 + di];
                    cg[0] = c0; cg[1024] = c1; cg[2048] = c2; cg[3072] = c3;
                }
            }
            if (lead) *(float4*)&sy[di][tt] = ppv;
        }
        __syncthreads();   // barD: sy complete; staging arrays free
        // ---- epilogue (registers for xi/z; sy only from LDS) ----
        if (part == 0) {
            const size_t r = (size_t)rbase + t0 + lr;
            ushort4 s0, s1;
            s0.x = f2bf(fmaf(bf2f(oxi0.x), dpv[0], sy[lc * 8 + 0][lr]) * silu_f(bf2f(pz0.x)));
            s0.y = f2bf(fmaf(bf2f(oxi0.y), dpv[1], sy[lc * 8 + 1][lr]) * silu_f(bf2f(pz0.y)));
            s0.z = f2bf(fmaf(bf2f(oxi0.z), dpv[2], sy[lc * 8 + 2][lr]) * silu_f(bf2f(pz0.z)));
            s0.w = f2bf(fmaf(bf2f(oxi0.w), dpv[3], sy[lc * 8 + 3][lr]) * silu_f(bf2f(pz0.w)));
            s1.x = f2bf(fmaf(bf2f(oxi1.x), dpv[4], sy[lc * 8 + 4][lr]) * silu_f(bf2f(pz1.x)));
            s1.y = f2bf(fmaf(bf2f(oxi1.y), dpv[5], sy[lc * 8 + 5][lr]) * silu_f(bf2f(pz1.y)));
            s1.z = f2bf(fmaf(bf2f(oxi1.z), dpv[6], sy[lc * 8 + 6][lr]) * silu_f(bf2f(pz1.z)));
            s1.w = f2bf(fmaf(bf2f(oxi1.w), dpv[7], sy[lc * 8 + 7][lr]) * silu_f(bf2f(pz1.w)));
            *(ushort4*)&xiy[r * 1024 + d0 + lc * 8] = s0;
            *(ushort4*)&xiy[r * 1024 + d0 + lc * 8 + 4] = s1;
        } else {
            const size_t pr = (size_t)(b * (LSEQ / 2) + t0 + lr) * 1024 + d0 + lc * 8;
            float4 w0, w1;
            w0.x = fmaf(bf2f(oxi0.x), dpv[0], sy[lc * 8 + 0][lr]);
            w0.y = fmaf(bf2f(oxi0.y), dpv[1], sy[lc * 8 + 1][lr]);
            w0.z = fmaf(bf2f(oxi0.z), dpv[2], sy[lc * 8 + 2][lr]);
            w0.w = fmaf(bf2f(oxi0.w), dpv[3], sy[lc * 8 + 3][lr]);
            w1.x = fmaf(bf2f(oxi1.x), dpv[4], sy[lc * 8 + 4][lr]);
            w1.y = fmaf(bf2f(oxi1.y), dpv[5], sy[lc * 8 + 5][lr]);
            w1.z = fmaf(bf2f(oxi1.z), dpv[6], sy[lc * 8 + 6][lr]);
            w1.w = fmaf(bf2f(oxi1.w), dpv[7], sy[lc * 8 + 7][lr]);
            *(float4*)&ydp[pr]     = w0;
            *(float4*)&ydp[pr + 4] = w1;
        }
    }
    if (part == 0) {
        float* hh = &hep[((size_t)b * 1024 + d0 + di) * 16 + np];
        hh[0] = h0; hh[8] = h1;
    }
}

// ---------------------------------------------------------------------------
// Part-1 fixup: y = yd + sum_n C_n * exp2(AL_n * cum) * h_start_n, then gate.
// Block: 64 ch x 4 rows. Fully parallel.
// ---------------------------------------------------------------------------
struct FixArgs {
    const float* yd[2]; const float* cumg[2]; const float* he[2];
    const float* al2[2]; const float* dbl[2]; const unsigned short* xz[2];
    unsigned short* xiy[2];
};
__global__ __launch_bounds__(256) void fix_k(FixArgs a)
{
    const int dir = blockIdx.z;
    const float* yd            = a.yd[dir];
    const float* cumg          = a.cumg[dir];
    const float* he            = a.he[dir];
    const float* al2           = a.al2[dir];
    const float* dbl           = a.dbl[dir];
    const unsigned short* xz   = a.xz[dir];
    unsigned short* xiy        = a.xiy[dir];

    __shared__ float sAL[64][17], sHE[64][17];
    __shared__ float sC[4][16];

    const int tid = threadIdx.x;
    const int d0 = blockIdx.x << 6;
    const int r0 = blockIdx.y << 2;          // local part-1 row
    const int b = r0 >> 10;
    for (int i = tid; i < 1024; i += 256) {
        const int dd = i >> 4, nn = i & 15;
        sAL[dd][nn] = al2[(size_t)(d0 + dd) * 16 + nn];
        sHE[dd][nn] = he[((size_t)b * 1024 + d0 + dd) * 16 + nn];
    }
    if (tid < 64) {
        const int rr = tid >> 4, n = tid & 15;
        sC[rr][n] = dbl[((size_t)b * LSEQ + (LSEQ / 2) + ((r0 + rr) & 1023)) * 64 + 48 + n];
    }
    __syncthreads();
    const int rr = tid >> 6, d = tid & 63;
    const int lrow = r0 + rr;
    const int t = (lrow & 1023) + (LSEQ / 2);
    const size_t grow = (size_t)b * LSEQ + t;
    const float cv = cumg[(size_t)lrow * 1024 + d0 + d];
    float corr = 0.f;
#pragma unroll
    for (int n = 0; n < 16; ++n)
        corr = fmaf(sC[rr][n] * sHE[d][n], EXP2F(sAL[d][n] * cv), corr);
    const float yv = yd[(size_t)lrow * 1024 + d0 + d] + corr;
    const int tz = dir ? (LSEQ - 1 - t) : t;
    const float z = bf2f(xz[((size_t)b * LSEQ + tz) * 2048 + 1024 + d0 + d]);
    xiy[grow * 1024 + d0 + d] = f2bf(yv * silu_f(z));
}

// ---------------------------------------------------------------------------
extern "C" void kernel_launch(void* const* d_in, const int* in_sizes, int n_in,
                              void* d_out, int out_size, void* d_ws, size_t ws_size,
                              hipStream_t stream)
{
    const float* x      = (const float*)d_in[0];
    const float* f_in_w = (const float*)d_in[1];
    const float* f_cw   = (const float*)d_in[2];
    const float* f_cb   = (const float*)d_in[3];
    const float* f_xp   = (const float*)d_in[4];
    const float* f_dtw  = (const float*)d_in[5];
    const float* f_dtb  = (const float*)d_in[6];
    const float* f_Al   = (const float*)d_in[7];
    const float* f_Dp   = (const float*)d_in[8];
    const float* f_ow   = (const float*)d_in[9];
    const float* b_in_w = (const float*)d_in[10];
    const float* b_cw   = (const float*)d_in[11];
    const float* b_cb   = (const float*)d_in[12];
    const float* b_xp   = (const float*)d_in[13];
    const float* b_dtw  = (const float*)d_in[14];
    const float* b_dtb  = (const float*)d_in[15];
    const float* b_Al   = (const float*)d_in[16];
    const float* b_Dp   = (const float*)d_in[17];
    const float* b_ow   = (const float*)d_in[18];
    const float* lin_w  = (const float*)d_in[19];
    const float* lin_b  = (const float*)d_in[20];
    float* out = (float*)d_out;

    char* p = (char*)d_ws;
    auto take = [&](size_t bytes) -> char* {
        char* r = p; p += (bytes + 255) & ~(size_t)255; return r;
    };

    // persistent bf16 weights + AL2 tables
    unsigned short* wif  = (unsigned short*)take((size_t)2048 * 512 * 2);
    unsigned short* wib  = (unsigned short*)take((size_t)2048 * 512 * 2);
    unsigned short* wxf  = (unsigned short*)take((size_t)64 * 1024 * 2);
    unsigned short* wxb  = (unsigned short*)take((size_t)64 * 1024 * 2);
    unsigned short* wdtf = (unsigned short*)take((size_t)1024 * 32 * 2);
    unsigned short* wdtb = (unsigned short*)take((size_t)1024 * 32 * 2);
    unsigned short* wcmb = (unsigned short*)take((size_t)512 * 2048 * 2);
    float* al2f = (float*)take((size_t)1024 * 16 * 4);
    float* al2b = (float*)take((size_t)1024 * 16 * 4);

    const size_t used = (size_t)(p - (char*)d_ws);
    // per-row bytes: xbf 1024 + per dir (xz 4096 + xiy 2048 + dbl 256 + dblh 64
    //                                    + cum 2048 + yd 2048)
    const size_t perRow = 1024 + 2 * (4096 + 2048 + 256 + 64 + 2048 + 2048);
    int G = 1;
    for (int g = 8; g >= 1; g >>= 1) {
        const size_t need = used + (size_t)g * LSEQ * perRow + (size_t)g * 2 * 1024 * 16 * 4 + 16384;
        if (need <= ws_size || g == 1) { G = g; break; }
    }

    CvtArgs ca;
    ca.s[0] = f_in_w; ca.d[0] = wif;  ca.n[0] = 2048 * 512;
    ca.s[1] = b_in_w; ca.d[1] = wib;  ca.n[1] = 2048 * 512;
    ca.s[2] = f_xp;   ca.d[2] = wxf;  ca.n[2] = 64 * 1024;
    ca.s[3] = b_xp;   ca.d[3] = wxb;  ca.n[3] = 64 * 1024;
    ca.s[4] = f_dtw;  ca.d[4] = wdtf; ca.n[4] = 1024 * 32;
    ca.s[5] = b_dtw;  ca.d[5] = wdtb; ca.n[5] = 1024 * 32;
    cvt_k<<<dim3(128, 6), 256, 0, stream>>>(ca);

    alprep_k<<<dim3(64), 256, 0, stream>>>(f_Al, b_Al, al2f, al2b);

    // combined (lin_w @ out_w) weight, bf16, (512 x 2048) — proven r7
    combine_k<<<dim3(4, 128, 2), 256, 0, stream>>>(lin_w, f_ow, b_ow, wcmb);

    char* pg0 = p;
    for (int g0 = 0; g0 < NBATCH; g0 += G) {
        const int Mg = G * LSEQ;
        p = pg0;
        unsigned short* xbf   = (unsigned short*)take((size_t)Mg * 512 * 2);
        unsigned short* xz_f  = (unsigned short*)take((size_t)Mg * 2048 * 2);
        unsigned short* xz_b  = (unsigned short*)take((size_t)Mg * 2048 * 2);
        unsigned short* xiy_f = (unsigned short*)take((size_t)Mg * 1024 * 2);
        unsigned short* xiy_b = (unsigned short*)take((size_t)Mg * 1024 * 2);
        float* dbl_f          = (float*)take((size_t)Mg * 64 * 4);
        float* dbl_b          = (float*)take((size_t)Mg * 64 * 4);
        unsigned short* dblh_f= (unsigned short*)take((size_t)Mg * 32 * 2);
        unsigned short* dblh_b= (unsigned short*)take((size_t)Mg * 32 * 2);
        float* cum_f          = (float*)take((size_t)G * 1024 * 1024 * 4);
        float* cum_b          = (float*)take((size_t)G * 1024 * 1024 * 4);
        float* yd_f           = (float*)take((size_t)G * 1024 * 1024 * 4);
        float* yd_b           = (float*)take((size_t)G * 1024 * 1024 * 4);
        float* he_f           = (float*)take((size_t)G * 1024 * 16 * 4);
        float* he_b           = (float*)take((size_t)G * 1024 * 16 * 4);

        const float* xg = x + (size_t)g0 * LSEQ * 512;
        float* outg = out + (size_t)g0 * LSEQ * 512;

        cvtx_k<<<dim3(512), 256, 0, stream>>>(xg, xbf, Mg * 512 / 4);

        GemmPair g1 = {};   // in-proj: xz = x @ in_w^T (N=2048), bf16 out
        g1.A[0] = xbf; g1.A[1] = xbf; g1.W[0] = wif; g1.W[1] = wib;
        g1.C[0] = xz_f; g1.C[1] = xz_b;
        gemm_mfma<2,2,1,0,0><<<dim3(Mg/128, 16, 2), 256, 0, stream>>>(g1, 512, 512, 2048, 512);

        conv_silu_k<<<dim3(Mg, 2), 256, 0, stream>>>(xz_f, f_cw, f_cb, xiy_f,
                                                     xz_b, b_cw, b_cb, xiy_b);

        GemmPair g2 = {};   // x-proj: dbl f32 (ldc 64) + bf16 cols<32 (dblh)
        g2.A[0] = xiy_f; g2.A[1] = xiy_b; g2.W[0] = wxf; g2.W[1] = wxb;
        g2.C[0] = dbl_f; g2.C[1] = dbl_b; g2.aux[0] = dblh_f; g2.aux[1] = dblh_b;
        gemm_mfma<4,1,0,0,1><<<dim3(Mg/256, 1, 2), 256, 0, stream>>>(g2, 1024, 1024, 64, 1024);

        ScanPair spp = {};  // scan: seq-split P=2, 1024 rows per block
        spp.dblh[0] = dblh_f; spp.dblh[1] = dblh_b;
        spp.dtw[0] = wdtf;    spp.dtw[1] = wdtb;
        spp.dtb[0] = f_dtb;   spp.dtb[1] = b_dtb;
        spp.xiy[0] = xiy_f;   spp.xiy[1] = xiy_b;
        spp.dbl[0] = dbl_f;   spp.dbl[1] = dbl_b;
        spp.xz[0] = xz_f;     spp.xz[1] = xz_b;
        spp.Al[0] = f_Al;     spp.Al[1] = b_Al;
        spp.Dp[0] = f_Dp;     spp.Dp[1] = b_Dp;
        spp.cumg[0] = cum_f;  spp.cumg[1] = cum_b;
        spp.yd[0] = yd_f;     spp.yd[1] = yd_b;
        spp.he[0] = he_f;     spp.he[1] = he_b;
        scan_k<<<dim3(32, G * 2, 2), 256, 0, stream>>>(spp);

        FixArgs fa = {};
        fa.yd[0] = yd_f;   fa.yd[1] = yd_b;
        fa.cumg[0] = cum_f; fa.cumg[1] = cum_b;
        fa.he[0] = he_f;   fa.he[1] = he_b;
        fa.al2[0] = al2f;  fa.al2[1] = al2b;
        fa.dbl[0] = dbl_f; fa.dbl[1] = dbl_b;
        fa.xz[0] = xz_f;   fa.xz[1] = xz_b;
        fa.xiy[0] = xiy_f; fa.xiy[1] = xiy_b;
        fix_k<<<dim3(16, G * 256, 2), 256, 0, stream>>>(fa);

        // fused out-proj+final: out = [y_f | rev(y_b)] @ Wcomb^T + lin_b (K=2048)
        GemmPair g5 = {};
        g5.A[0] = xiy_f; g5.A2[0] = xiy_b; g5.W[0] = wcmb;
        g5.bias[0] = lin_b; g5.C[0] = outg;
        gemm_mfma<2,2,0,1024,0><<<dim3(Mg/128, 4, 1), 256, 0, stream>>>(g5, 1024, 2048, 512, 2048);
    }
}

// Round 4
// 908.074 us; speedup vs baseline: 1.0371x; 1.0371x over previous
//
#include <hip/hip_runtime.h>
#include <cmath>

#define LSEQ 2048
#define NBATCH 8

typedef __attribute__((ext_vector_type(8))) short short8;
typedef __attribute__((ext_vector_type(4))) float f32x4;

__device__ __forceinline__ float silu_f(float x) {
    return x * __builtin_amdgcn_rcpf(1.0f + __expf(-x));
}
__device__ __forceinline__ float softplus_f(float x) {
    return fmaxf(x, 0.0f) + __logf(1.0f + __expf(-fabsf(x)));
}
__device__ __forceinline__ unsigned short f2bf(float f) {   // RNE fp32->bf16
    unsigned int u = __float_as_uint(f);
    u += 0x7FFFu + ((u >> 16) & 1u);
    return (unsigned short)(u >> 16);
}
__device__ __forceinline__ float bf2f(unsigned short h) {
    return __uint_as_float(((unsigned int)h) << 16);
}
__device__ __forceinline__ void gload_lds16(const void* g, void* l) {
    __builtin_amdgcn_global_load_lds((const __attribute__((address_space(1))) void*)g,
                                     (__attribute__((address_space(3))) void*)l, 16, 0, 0);
}

#if defined(__has_builtin)
#if __has_builtin(__builtin_amdgcn_exp2f)
#define EXP2F(x) __builtin_amdgcn_exp2f(x)
#endif
#endif
#ifndef EXP2F
#define EXP2F(x) __expf((x) * 0.69314718055994531f)
#endif

// fwd/bwd operand pairs; blockIdx.z selects direction
struct GemmPair {
    const unsigned short* A[2];
    const unsigned short* A2[2];   // DUAL second A (second K-half, row-reversed)
    const unsigned short* W[2];
    const float* bias[2];
    void* C[2];
    unsigned short* aux[2];
};

// ---------------------------------------------------------------------------
// bf16 MFMA GEMM (NT), r4-proven config: BK=32, scalar epilogue.
// ---------------------------------------------------------------------------
template<int WGM, int WGN, int OMODE, int DK, int XTRA>
__global__ __launch_bounds__(WGM* WGN * 64) void gemm_mfma(GemmPair gp, int lda, int ldw,
                                                           int ldc, int K)
{
    constexpr int NW = WGM * WGN;
    constexpr int TM = WGM * 64, TN = WGN * 64;
    __shared__ unsigned short As[TM * 32];
    __shared__ unsigned short Bs[TN * 32];
    const int dir = blockIdx.z;
    const unsigned short* A  = gp.A[dir];
    const unsigned short* A2 = gp.A2[dir];
    const unsigned short* W  = gp.W[dir];
    const float* bias        = gp.bias[dir];
    void* Cout               = gp.C[dir];
    unsigned short* aux      = gp.aux[dir];

    const int tid = threadIdx.x;
    const int wave = tid >> 6, lane = tid & 63;
    const int wm = wave / WGN, wn = wave % WGN;
    const int m0 = blockIdx.x * TM, n0 = blockIdx.y * TN;
    const int l15 = lane & 15, l4 = lane >> 4;
    const int srow = lane >> 2, schunk = (lane & 3) * 8;

    f32x4 acc[4][4] = {};

    for (int k0 = 0; k0 < K; k0 += 32) {
        __syncthreads();
        for (int s = wave; s < TM / 16; s += NW) {
            const int gr = m0 + s * 16 + srow;
            const unsigned short* g;
            if (DK != 0 && k0 >= DK)
                g = A2 + (size_t)(gr ^ (LSEQ - 1)) * lda + (k0 - DK) + schunk;
            else
                g = A + (size_t)gr * lda + k0 + schunk;
            gload_lds16(g, (char*)As + (size_t)s * 1024);
        }
        for (int s = wave; s < TN / 16; s += NW) {
            const int gr = n0 + s * 16 + srow;
            const unsigned short* g = W + (size_t)gr * ldw + k0 + schunk;
            gload_lds16(g, (char*)Bs + (size_t)s * 1024);
        }
        __syncthreads();
        short8 af[4], bfr[4];
#pragma unroll
        for (int mi = 0; mi < 4; ++mi)
            af[mi] = *(const short8*)&As[(wm * 64 + mi * 16 + l15) * 32 + l4 * 8];
#pragma unroll
        for (int ni = 0; ni < 4; ++ni)
            bfr[ni] = *(const short8*)&Bs[(wn * 64 + ni * 16 + l15) * 32 + l4 * 8];
#pragma unroll
        for (int mi = 0; mi < 4; ++mi)
#pragma unroll
            for (int ni = 0; ni < 4; ++ni)
                acc[mi][ni] = __builtin_amdgcn_mfma_f32_16x16x32_bf16(af[mi], bfr[ni], acc[mi][ni], 0, 0, 0);
    }

#pragma unroll
    for (int mi = 0; mi < 4; ++mi)
#pragma unroll
        for (int ni = 0; ni < 4; ++ni)
#pragma unroll
            for (int r = 0; r < 4; ++r) {
                const int row = m0 + wm * 64 + mi * 16 + l4 * 4 + r;
                const int col = n0 + wn * 64 + ni * 16 + l15;
                float v = acc[mi][ni][r];
                if (bias) v += bias[col];
                if (OMODE & 1) ((unsigned short*)Cout)[(size_t)row * ldc + col] = f2bf(v);
                else           ((float*)Cout)[(size_t)row * ldc + col] = v;
                if (XTRA) { if (col < 32) aux[(size_t)row * 32 + col] = f2bf(v); }
            }
}

// ---------------------------------------------------------------------------
// Combined weight for fused out-proj+final (proven r7: identical absmax):
// ---------------------------------------------------------------------------
__global__ __launch_bounds__(256) void combine_k(
    const float* __restrict__ lin_w, const float* __restrict__ owf,
    const float* __restrict__ owb, unsigned short* __restrict__ Wcomb)
{
    const int dir = blockIdx.z;
    const float* ow = dir ? owb : owf;
    const int lane = threadIdx.x & 63;
    const int wave = threadIdx.x >> 6;
    const int n = blockIdx.y * 4 + wave;          // 0..511
    const int d = blockIdx.x * 256 + lane * 4;    // 0..1023
    float4 acc = {0.f, 0.f, 0.f, 0.f};
    const float* lrow = lin_w + (size_t)n * 1024 + dir * 512;
    for (int j = 0; j < 512; ++j) {
        const float s = lrow[j];
        const float4 v = *(const float4*)&ow[(size_t)j * 1024 + d];
        acc.x = fmaf(s, v.x, acc.x); acc.y = fmaf(s, v.y, acc.y);
        acc.z = fmaf(s, v.z, acc.z); acc.w = fmaf(s, v.w, acc.w);
    }
    ushort4 o;
    o.x = f2bf(acc.x); o.y = f2bf(acc.y); o.z = f2bf(acc.z); o.w = f2bf(acc.w);
    *(ushort4*)&Wcomb[(size_t)n * 2048 + dir * 1024 + d] = o;
}

// ---------------------------------------------------------------------------
// fp32 -> bf16 conversion: 6 weight segments, one launch.
// ---------------------------------------------------------------------------
struct CvtArgs { const float* s[6]; unsigned short* d[6]; int n[6]; };
__global__ __launch_bounds__(256) void cvt_k(CvtArgs a)
{
    const int sid = blockIdx.y;
    const float* s = a.s[sid];
    unsigned short* d = a.d[sid];
    const int n4 = a.n[sid] >> 2;
    for (int i = blockIdx.x * 256 + threadIdx.x; i < n4; i += gridDim.x * 256) {
        const float4 v = ((const float4*)s)[i];
        ushort4 o; o.x = f2bf(v.x); o.y = f2bf(v.y); o.z = f2bf(v.z); o.w = f2bf(v.w);
        ((ushort4*)d)[i] = o;
    }
}
__global__ __launch_bounds__(256) void cvtx_k(const float* __restrict__ s,
                                              unsigned short* __restrict__ d, int n4)
{
    for (int i = blockIdx.x * 256 + threadIdx.x; i < n4; i += gridDim.x * 256) {
        const float4 v = ((const float4*)s)[i];
        ushort4 o; o.x = f2bf(v.x); o.y = f2bf(v.y); o.z = f2bf(v.z); o.w = f2bf(v.w);
        ((ushort4*)d)[i] = o;
    }
}

// A_log -> -exp(A_log)*log2(e) tables for both dirs (used by fix_k)
__global__ __launch_bounds__(256) void alprep_k(const float* __restrict__ af,
                                                const float* __restrict__ ab,
                                                float* __restrict__ of,
                                                float* __restrict__ ob)
{
    const int i = blockIdx.x * 256 + threadIdx.x;
    if (i < 16384) {
        of[i] = -expf(af[i]) * 1.4426950408889634f;
        ob[i] = -expf(ab[i]) * 1.4426950408889634f;
    }
}

// ---------------------------------------------------------------------------
// Causal depthwise conv(4) + bias + SiLU, both dirs.
// ---------------------------------------------------------------------------
__global__ __launch_bounds__(256) void conv_silu_k(
    const unsigned short* __restrict__ xz_f, const float* __restrict__ cw_f,
    const float* __restrict__ cb_f, unsigned short* __restrict__ xi_f,
    const unsigned short* __restrict__ xz_b, const float* __restrict__ cw_b,
    const float* __restrict__ cb_b, unsigned short* __restrict__ xi_b)
{
    const int dir = blockIdx.y;
    const unsigned short* xz = dir ? xz_b : xz_f;
    const float* cw = dir ? cw_b : cw_f;
    const float* cb = dir ? cb_b : cb_f;
    unsigned short* xi = dir ? xi_b : xi_f;

    const int bt = blockIdx.x;
    const int b = bt >> 11;
    const int t = bt & (LSEQ - 1);
    const int d = threadIdx.x << 2;

    float w[4][4];
#pragma unroll
    for (int i = 0; i < 4; ++i) {
        const float4 wr = *(const float4*)&cw[(d + i) * 4];
        w[i][0] = wr.x; w[i][1] = wr.y; w[i][2] = wr.z; w[i][3] = wr.w;
    }
    float4 acc = *(const float4*)&cb[d];
#pragma unroll
    for (int k = 0; k < 4; ++k) {
        const int row = dir ? (LSEQ - 1 - t) + 3 - k : t - 3 + k;
        if ((unsigned)row < (unsigned)LSEQ) {
            const ushort4 v = *(const ushort4*)&xz[(size_t)(b * LSEQ + row) * 2048 + d];
            acc.x += w[0][k] * bf2f(v.x); acc.y += w[1][k] * bf2f(v.y);
            acc.z += w[2][k] * bf2f(v.z); acc.w += w[3][k] * bf2f(v.w);
        }
    }
    ushort4 st;
    st.x = f2bf(silu_f(acc.x)); st.y = f2bf(silu_f(acc.y));
    st.z = f2bf(silu_f(acc.z)); st.w = f2bf(silu_f(acc.w));
    *(ushort4*)&xi[(size_t)(b * LSEQ + t) * 1024 + d] = st;
}

// ---------------------------------------------------------------------------
// Selective scan, seq-split P=2 (round 4):
//  - part 0: full scan + gated epilogue + h_end (he).
//  - part 1: local scan from h=0; epilogue writes raw y+xi*Dp as bf16
//    IN PLACE into xiy (no yd array) and cum (f32) via scum LDS staging
//    (coalesced float4 rows). fix_k applies correction + gating.
// ---------------------------------------------------------------------------
__device__ __forceinline__ float row_sum8(float x) {
    x += __int_as_float(__builtin_amdgcn_update_dpp(0, __float_as_int(x), 0xB1, 0xF, 0xF, true));  // quad xor1
    x += __int_as_float(__builtin_amdgcn_update_dpp(0, __float_as_int(x), 0x4E, 0xF, 0xF, true));  // quad xor2
    x += __int_as_float(__builtin_amdgcn_update_dpp(0, __float_as_int(x), 0x141, 0xF, 0xF, true)); // row_half_mirror
    return x;
}

struct ScanPair {
    const unsigned short* dblh[2];   // (rows x 32) bf16
    const unsigned short* dtw[2];    // (1024 x 32) bf16
    const float* dtb[2];             // (1024) f32
    unsigned short* xiy[2];          // (rows x 1024) bf16, in/out
    const float* dbl[2];             // (rows x 64) f32, B/C in cols 32..63
    const unsigned short* xz[2];     // (rows x 2048) bf16, z in cols 1024+
    const float* Al[2];
    const float* Dp[2];
    float* cumg[2];                  // (G*1024 x 1024) f32: part-1 cumsum(dt)
    float* he[2];                    // (G*1024 x 16) f32: part-0 h_end
};

__global__ __launch_bounds__(256, 3) void scan_k(ScanPair sp)
{
    __shared__ unsigned short sxi[64][40];       // [t][ch] raw bf16
    __shared__ float sdt[32][68], sdtx[32][68];  // [ch][t]
    __shared__ float sB2[8][140], sC2[8][140];   // [np][t*2+half]: {B_np, B_np+8}
    __shared__ float sy[32][68];                 // [ch][t]
    __shared__ float scum[32][68];               // [ch][t] (part 1 only)

    const int dir = blockIdx.z;
    const unsigned short* dblh = sp.dblh[dir];
    const unsigned short* dtw  = sp.dtw[dir];
    const float* dtb           = sp.dtb[dir];
    unsigned short* xiy        = sp.xiy[dir];
    const float* dbl           = sp.dbl[dir];
    const unsigned short* zz   = sp.xz[dir];
    const float* Al            = sp.Al[dir];
    const float* Dpp           = sp.Dp[dir];
    float* cumg                = sp.cumg[dir];
    float* hep                 = sp.he[dir];

    const int by = blockIdx.y;
    const int b = by >> 1, part = by & 1;
    const int rbase = b * LSEQ + part * (LSEQ / 2);
    const int d0 = blockIdx.x << 5;
    const int tid = threadIdx.x;
    const int wave = tid >> 6, lane = tid & 63;
    const int l15 = lane & 15, l4 = lane >> 4;
    const int di = tid >> 3, np = tid & 7;     // inner-loop mapping
    const int lr = tid >> 2, lc = tid & 3;     // stage/epilogue mapping
    const bool lead = (np == 0);

    // A constants pre-scaled by log2(e) so exp2 needs no extra mul
    const float A0L = -expf(Al[(d0 + di) * 16 + np]) * 1.4426950408889634f;
    const float A1L = -expf(Al[(d0 + di) * 16 + np + 8]) * 1.4426950408889634f;

    // dt MFMA B-fragments: rows = the block's 32 channels (two 16-ch halves)
    const short8 dtwf0 = *(const short8*)&dtw[(size_t)(d0 + l15) * 32 + l4 * 8];
    const short8 dtwf1 = *(const short8*)&dtw[(size_t)(d0 + 16 + l15) * 32 + l4 * 8];
    const float dtb0 = dtb[d0 + l15], dtb1 = dtb[d0 + 16 + l15];

    float dpv[8];
#pragma unroll
    for (int i = 0; i < 8; ++i) dpv[i] = Dpp[d0 + lc * 8 + i];

    ushort4 pxi0, pxi1;
    float4 pB, pC;
    short8 pA;
    auto issue_loads = [&](int c) {
        const size_t r = (size_t)rbase + c * 64 + lr;
        pxi0 = *(const ushort4*)&xiy[r * 1024 + d0 + lc * 8];
        pxi1 = *(const ushort4*)&xiy[r * 1024 + d0 + lc * 8 + 4];
        pB   = *(const float4*)&dbl[r * 64 + 32 + lc * 4];
        pC   = *(const float4*)&dbl[r * 64 + 48 + lc * 4];
        // dt MFMA A-fragment: rows = this wave's 16 timesteps of the chunk
        pA   = *(const short8*)&dblh[(size_t)(rbase + c * 64 + wave * 16 + l15) * 32 + l4 * 8];
    };
    issue_loads(0);

    constexpr int NT = (LSEQ / 2) / 64;   // 16 chunks per partition
    float h0 = 0.0f, h1 = 0.0f, cum = 0.0f;
    for (int c = 0; c < NT; ++c) {
        const int t0 = c * 64;
        // ---- stage xi raw bf16 [t][ch] and B/C pairs ----
        *(ushort4*)&sxi[lr][lc * 8]     = pxi0;
        *(ushort4*)&sxi[lr][lc * 8 + 4] = pxi1;
        {
            const float bv[4] = {pB.x, pB.y, pB.z, pB.w};
            const float cv[4] = {pC.x, pC.y, pC.z, pC.w};
#pragma unroll
            for (int i = 0; i < 4; ++i) {
                const int n = lc * 4 + i;
                sB2[n & 7][lr * 2 + (n >> 3)] = bv[i];
                sC2[n & 7][lr * 2 + (n >> 3)] = cv[i];
            }
        }
        __syncthreads();   // barC-pre: stage visible to all
        // ---- dt phase: MFMA -> softplus -> sdt, and dtx = dt*xi -> sdtx ----
        {
            f32x4 z4 = {0.f, 0.f, 0.f, 0.f};
            f32x4 dacc0 = __builtin_amdgcn_mfma_f32_16x16x32_bf16(pA, dtwf0, z4, 0, 0, 0);
            f32x4 dacc1 = __builtin_amdgcn_mfma_f32_16x16x32_bf16(pA, dtwf1, z4, 0, 0, 0);
            const int tq = wave * 16 + l4 * 4;
            float4 xi0, xi1;
            xi0.x = bf2f(sxi[tq + 0][l15]);      xi0.y = bf2f(sxi[tq + 1][l15]);
            xi0.z = bf2f(sxi[tq + 2][l15]);      xi0.w = bf2f(sxi[tq + 3][l15]);
            xi1.x = bf2f(sxi[tq + 0][16 + l15]); xi1.y = bf2f(sxi[tq + 1][16 + l15]);
            xi1.z = bf2f(sxi[tq + 2][16 + l15]); xi1.w = bf2f(sxi[tq + 3][16 + l15]);
            float4 dv0, dv1, dx0, dx1;
            dv0.x = softplus_f(dacc0[0] + dtb0); dv0.y = softplus_f(dacc0[1] + dtb0);
            dv0.z = softplus_f(dacc0[2] + dtb0); dv0.w = softplus_f(dacc0[3] + dtb0);
            dv1.x = softplus_f(dacc1[0] + dtb1); dv1.y = softplus_f(dacc1[1] + dtb1);
            dv1.z = softplus_f(dacc1[2] + dtb1); dv1.w = softplus_f(dacc1[3] + dtb1);
            dx0.x = dv0.x * xi0.x; dx0.y = dv0.y * xi0.y;
            dx0.z = dv0.z * xi0.z; dx0.w = dv0.w * xi0.w;
            dx1.x = dv1.x * xi1.x; dx1.y = dv1.y * xi1.y;
            dx1.z = dv1.z * xi1.z; dx1.w = dv1.w * xi1.w;
            *(float4*)&sdt[l15][tq]       = dv0;
            *(float4*)&sdt[16 + l15][tq]  = dv1;
            *(float4*)&sdtx[l15][tq]      = dx0;
            *(float4*)&sdtx[16 + l15][tq] = dx1;
        }
        const ushort4 oxi0 = pxi0, oxi1 = pxi1;
        ushort4 pz0 = {}, pz1 = {};
        if (part == 0) {
            const int tg = t0 + lr;
            const int tz = dir ? (LSEQ - 1 - tg) : tg;
            pz0 = *(const ushort4*)&zz[((size_t)b * LSEQ + tz) * 2048 + 1024 + d0 + lc * 8];
            pz1 = *(const ushort4*)&zz[((size_t)b * LSEQ + tz) * 2048 + 1024 + d0 + lc * 8 + 4];
        }
        if (c + 1 < NT) issue_loads(c + 1);
        __syncthreads();   // barC: sdt/sdtx visible, inner may start
        // ---- inner scan: 64 timesteps, 2 states per thread ----
#pragma unroll 4
        for (int tt = 0; tt < 64; tt += 4) {
            const float4 d4 = *(const float4*)&sdt[di][tt];
            const float4 u4 = *(const float4*)&sdtx[di][tt];
            const float4 bA = *(const float4*)&sB2[np][tt * 2];
            const float4 bB = *(const float4*)&sB2[np][tt * 2 + 4];
            const float4 cA = *(const float4*)&sC2[np][tt * 2];
            const float4 cB = *(const float4*)&sC2[np][tt * 2 + 4];
            float4 ppv;
            h0 = fmaf(EXP2F(d4.x * A0L), h0, u4.x * bA.x);
            h1 = fmaf(EXP2F(d4.x * A1L), h1, u4.x * bA.y);
            ppv.x = row_sum8(fmaf(h1, cA.y, h0 * cA.x));
            h0 = fmaf(EXP2F(d4.y * A0L), h0, u4.y * bA.z);
            h1 = fmaf(EXP2F(d4.y * A1L), h1, u4.y * bA.w);
            ppv.y = row_sum8(fmaf(h1, cA.w, h0 * cA.z));
            h0 = fmaf(EXP2F(d4.z * A0L), h0, u4.z * bB.x);
            h1 = fmaf(EXP2F(d4.z * A1L), h1, u4.z * bB.y);
            ppv.z = row_sum8(fmaf(h1, cB.y, h0 * cB.x));
            h0 = fmaf(EXP2F(d4.w * A0L), h0, u4.w * bB.z);
            h1 = fmaf(EXP2F(d4.w * A1L), h1, u4.w * bB.w);
            ppv.w = row_sum8(fmaf(h1, cB.w, h0 * cB.z));
            if (part) {
                const float c0 = cum + d4.x, c1 = c0 + d4.y;
                const float c2 = c1 + d4.z, c3 = c2 + d4.w;
                cum = c3;
                if (lead) {
                    float4 cc; cc.x = c0; cc.y = c1; cc.z = c2; cc.w = c3;
                    *(float4*)&scum[di][tt] = cc;
                }
            }
            if (lead) *(float4*)&sy[di][tt] = ppv;
        }
        __syncthreads();   // barD: sy/scum complete; staging arrays free
        // ---- epilogue ----
        if (part == 0) {
            const size_t r = (size_t)rbase + t0 + lr;
            ushort4 s0, s1;
            s0.x = f2bf(fmaf(bf2f(oxi0.x), dpv[0], sy[lc * 8 + 0][lr]) * silu_f(bf2f(pz0.x)));
            s0.y = f2bf(fmaf(bf2f(oxi0.y), dpv[1], sy[lc * 8 + 1][lr]) * silu_f(bf2f(pz0.y)));
            s0.z = f2bf(fmaf(bf2f(oxi0.z), dpv[2], sy[lc * 8 + 2][lr]) * silu_f(bf2f(pz0.z)));
            s0.w = f2bf(fmaf(bf2f(oxi0.w), dpv[3], sy[lc * 8 + 3][lr]) * silu_f(bf2f(pz0.w)));
            s1.x = f2bf(fmaf(bf2f(oxi1.x), dpv[4], sy[lc * 8 + 4][lr]) * silu_f(bf2f(pz1.x)));
            s1.y = f2bf(fmaf(bf2f(oxi1.y), dpv[5], sy[lc * 8 + 5][lr]) * silu_f(bf2f(pz1.y)));
            s1.z = f2bf(fmaf(bf2f(oxi1.z), dpv[6], sy[lc * 8 + 6][lr]) * silu_f(bf2f(pz1.z)));
            s1.w = f2bf(fmaf(bf2f(oxi1.w), dpv[7], sy[lc * 8 + 7][lr]) * silu_f(bf2f(pz1.w)));
            *(ushort4*)&xiy[r * 1024 + d0 + lc * 8] = s0;
            *(ushort4*)&xiy[r * 1024 + d0 + lc * 8 + 4] = s1;
        } else {
            // raw y + xi*Dp as bf16 in place; cum coalesced f32
            const size_t r = (size_t)rbase + t0 + lr;
            ushort4 s0, s1;
            s0.x = f2bf(fmaf(bf2f(oxi0.x), dpv[0], sy[lc * 8 + 0][lr]));
            s0.y = f2bf(fmaf(bf2f(oxi0.y), dpv[1], sy[lc * 8 + 1][lr]));
            s0.z = f2bf(fmaf(bf2f(oxi0.z), dpv[2], sy[lc * 8 + 2][lr]));
            s0.w = f2bf(fmaf(bf2f(oxi0.w), dpv[3], sy[lc * 8 + 3][lr]));
            s1.x = f2bf(fmaf(bf2f(oxi1.x), dpv[4], sy[lc * 8 + 4][lr]));
            s1.y = f2bf(fmaf(bf2f(oxi1.y), dpv[5], sy[lc * 8 + 5][lr]));
            s1.z = f2bf(fmaf(bf2f(oxi1.z), dpv[6], sy[lc * 8 + 6][lr]));
            s1.w = f2bf(fmaf(bf2f(oxi1.w), dpv[7], sy[lc * 8 + 7][lr]));
            *(ushort4*)&xiy[r * 1024 + d0 + lc * 8] = s0;
            *(ushort4*)&xiy[r * 1024 + d0 + lc * 8 + 4] = s1;
            float4 c0v, c1v;
            c0v.x = scum[lc * 8 + 0][lr]; c0v.y = scum[lc * 8 + 1][lr];
            c0v.z = scum[lc * 8 + 2][lr]; c0v.w = scum[lc * 8 + 3][lr];
            c1v.x = scum[lc * 8 + 4][lr]; c1v.y = scum[lc * 8 + 5][lr];
            c1v.z = scum[lc * 8 + 6][lr]; c1v.w = scum[lc * 8 + 7][lr];
            const size_t pr = (size_t)(b * (LSEQ / 2) + t0 + lr) * 1024 + d0 + lc * 8;
            *(float4*)&cumg[pr]     = c0v;
            *(float4*)&cumg[pr + 4] = c1v;
        }
    }
    if (part == 0) {
        float* hh = &hep[((size_t)b * 1024 + d0 + di) * 16 + np];
        hh[0] = h0; hh[8] = h1;
    }
}

// ---------------------------------------------------------------------------
// Part-1 fixup (round 4): block = 32 ch x 256 t-quarter x batch; AL/HE/C
// staged ONCE in LDS, loop over 32 iterations of 8 t. In-place on xiy.
// y = yd + sum_n C[t,n]*HE[d,n]*exp2(AL[d,n]*cum[t,d]), then gate silu(z).
// ---------------------------------------------------------------------------
struct FixArgs {
    const float* cumg[2]; const float* he[2]; const float* al2[2];
    const float* dbl[2];  const unsigned short* xz[2]; unsigned short* xiy[2];
};
__global__ __launch_bounds__(256) void fix_k(FixArgs a)
{
    const int dir = blockIdx.z;
    const float* cumg          = a.cumg[dir];
    const float* he            = a.he[dir];
    const float* al2           = a.al2[dir];
    const float* dbl           = a.dbl[dir];
    const unsigned short* xz   = a.xz[dir];
    unsigned short* xiy        = a.xiy[dir];

    __shared__ float sAL[32][17], sHE[32][17];
    __shared__ float sCt[256][16];

    const int tid = threadIdx.x;
    const int d0 = blockIdx.x << 5;           // 32-ch block
    const int by = blockIdx.y;
    const int b = by >> 2, q = by & 3;        // quarter (256 t) of part 1
    const int tq0 = q << 8;

    for (int i = tid; i < 512; i += 256) {
        const int dd = i >> 4, nn = i & 15;
        sAL[dd][nn] = al2[(size_t)(d0 + dd) * 16 + nn];
        sHE[dd][nn] = he[((size_t)b * 1024 + d0 + dd) * 16 + nn];
    }
    for (int i = tid; i < 4096; i += 256) {
        const int tt = i >> 4, nn = i & 15;
        sCt[tt][nn] = dbl[((size_t)b * LSEQ + (LSEQ / 2) + tq0 + tt) * 64 + 48 + nn];
    }
    __syncthreads();

    const int ts = tid >> 5, dd = tid & 31;
    for (int it = 0; it < 32; ++it) {
        const int tl = tq0 + it * 8 + ts;                 // part-local t
        const int tc = (it * 8 + ts) + (q << 8) - tq0 + 0; // == it*8+ts within quarter
        const int tglob = (LSEQ / 2) + tl;
        const size_t grow = (size_t)b * LSEQ + tglob;
        const float cv = cumg[((size_t)b * (LSEQ / 2) + tl) * 1024 + d0 + dd];
        const float yv0 = bf2f(xiy[grow * 1024 + d0 + dd]);
        const int tz = dir ? (LSEQ - 1 - tglob) : tglob;
        const float z = bf2f(xz[((size_t)b * LSEQ + tz) * 2048 + 1024 + d0 + dd]);
        float corr = 0.f;
#pragma unroll
        for (int n = 0; n < 16; ++n)
            corr = fmaf(sCt[it * 8 + ts][n] * sHE[dd][n], EXP2F(sAL[dd][n] * cv), corr);
        xiy[grow * 1024 + d0 + dd] = f2bf((yv0 + corr) * silu_f(z));
    }
}

// ---------------------------------------------------------------------------
extern "C" void kernel_launch(void* const* d_in, const int* in_sizes, int n_in,
                              void* d_out, int out_size, void* d_ws, size_t ws_size,
                              hipStream_t stream)
{
    const float* x      = (const float*)d_in[0];
    const float* f_in_w = (const float*)d_in[1];
    const float* f_cw   = (const float*)d_in[2];
    const float* f_cb   = (const float*)d_in[3];
    const float* f_xp   = (const float*)d_in[4];
    const float* f_dtw  = (const float*)d_in[5];
    const float* f_dtb  = (const float*)d_in[6];
    const float* f_Al   = (const float*)d_in[7];
    const float* f_Dp   = (const float*)d_in[8];
    const float* f_ow   = (const float*)d_in[9];
    const float* b_in_w = (const float*)d_in[10];
    const float* b_cw   = (const float*)d_in[11];
    const float* b_cb   = (const float*)d_in[12];
    const float* b_xp   = (const float*)d_in[13];
    const float* b_dtw  = (const float*)d_in[14];
    const float* b_dtb  = (const float*)d_in[15];
    const float* b_Al   = (const float*)d_in[16];
    const float* b_Dp   = (const float*)d_in[17];
    const float* b_ow   = (const float*)d_in[18];
    const float* lin_w  = (const float*)d_in[19];
    const float* lin_b  = (const float*)d_in[20];
    float* out = (float*)d_out;

    char* p = (char*)d_ws;
    auto take = [&](size_t bytes) -> char* {
        char* r = p; p += (bytes + 255) & ~(size_t)255; return r;
    };

    // persistent bf16 weights + AL2 tables
    unsigned short* wif  = (unsigned short*)take((size_t)2048 * 512 * 2);
    unsigned short* wib  = (unsigned short*)take((size_t)2048 * 512 * 2);
    unsigned short* wxf  = (unsigned short*)take((size_t)64 * 1024 * 2);
    unsigned short* wxb  = (unsigned short*)take((size_t)64 * 1024 * 2);
    unsigned short* wdtf = (unsigned short*)take((size_t)1024 * 32 * 2);
    unsigned short* wdtb = (unsigned short*)take((size_t)1024 * 32 * 2);
    unsigned short* wcmb = (unsigned short*)take((size_t)512 * 2048 * 2);
    float* al2f = (float*)take((size_t)1024 * 16 * 4);
    float* al2b = (float*)take((size_t)1024 * 16 * 4);

    const size_t used = (size_t)(p - (char*)d_ws);
    // per-row bytes: xbf 1024 + per dir (xz 4096 + xiy 2048 + dbl 256 + dblh 64
    //                                    + cum 2048)
    const size_t perRow = 1024 + 2 * (4096 + 2048 + 256 + 64 + 2048);
    int G = 1;
    for (int g = 8; g >= 1; g >>= 1) {
        const size_t need = used + (size_t)g * LSEQ * perRow + (size_t)g * 2 * 1024 * 16 * 4 + 16384;
        if (need <= ws_size || g == 1) { G = g; break; }
    }

    CvtArgs ca;
    ca.s[0] = f_in_w; ca.d[0] = wif;  ca.n[0] = 2048 * 512;
    ca.s[1] = b_in_w; ca.d[1] = wib;  ca.n[1] = 2048 * 512;
    ca.s[2] = f_xp;   ca.d[2] = wxf;  ca.n[2] = 64 * 1024;
    ca.s[3] = b_xp;   ca.d[3] = wxb;  ca.n[3] = 64 * 1024;
    ca.s[4] = f_dtw;  ca.d[4] = wdtf; ca.n[4] = 1024 * 32;
    ca.s[5] = b_dtw;  ca.d[5] = wdtb; ca.n[5] = 1024 * 32;
    cvt_k<<<dim3(128, 6), 256, 0, stream>>>(ca);

    alprep_k<<<dim3(64), 256, 0, stream>>>(f_Al, b_Al, al2f, al2b);

    // combined (lin_w @ out_w) weight, bf16, (512 x 2048) — proven r7
    combine_k<<<dim3(4, 128, 2), 256, 0, stream>>>(lin_w, f_ow, b_ow, wcmb);

    char* pg0 = p;
    for (int g0 = 0; g0 < NBATCH; g0 += G) {
        const int Mg = G * LSEQ;
        p = pg0;
        unsigned short* xbf   = (unsigned short*)take((size_t)Mg * 512 * 2);
        unsigned short* xz_f  = (unsigned short*)take((size_t)Mg * 2048 * 2);
        unsigned short* xz_b  = (unsigned short*)take((size_t)Mg * 2048 * 2);
        unsigned short* xiy_f = (unsigned short*)take((size_t)Mg * 1024 * 2);
        unsigned short* xiy_b = (unsigned short*)take((size_t)Mg * 1024 * 2);
        float* dbl_f          = (float*)take((size_t)Mg * 64 * 4);
        float* dbl_b          = (float*)take((size_t)Mg * 64 * 4);
        unsigned short* dblh_f= (unsigned short*)take((size_t)Mg * 32 * 2);
        unsigned short* dblh_b= (unsigned short*)take((size_t)Mg * 32 * 2);
        float* cum_f          = (float*)take((size_t)G * 1024 * 1024 * 4);
        float* cum_b          = (float*)take((size_t)G * 1024 * 1024 * 4);
        float* he_f           = (float*)take((size_t)G * 1024 * 16 * 4);
        float* he_b           = (float*)take((size_t)G * 1024 * 16 * 4);

        const float* xg = x + (size_t)g0 * LSEQ * 512;
        float* outg = out + (size_t)g0 * LSEQ * 512;

        cvtx_k<<<dim3(512), 256, 0, stream>>>(xg, xbf, Mg * 512 / 4);

        GemmPair g1 = {};   // in-proj: xz = x @ in_w^T (N=2048), bf16 out
        g1.A[0] = xbf; g1.A[1] = xbf; g1.W[0] = wif; g1.W[1] = wib;
        g1.C[0] = xz_f; g1.C[1] = xz_b;
        gemm_mfma<2,2,1,0,0><<<dim3(Mg/128, 16, 2), 256, 0, stream>>>(g1, 512, 512, 2048, 512);

        conv_silu_k<<<dim3(Mg, 2), 256, 0, stream>>>(xz_f, f_cw, f_cb, xiy_f,
                                                     xz_b, b_cw, b_cb, xiy_b);

        GemmPair g2 = {};   // x-proj: dbl f32 (ldc 64) + bf16 cols<32 (dblh)
        g2.A[0] = xiy_f; g2.A[1] = xiy_b; g2.W[0] = wxf; g2.W[1] = wxb;
        g2.C[0] = dbl_f; g2.C[1] = dbl_b; g2.aux[0] = dblh_f; g2.aux[1] = dblh_b;
        gemm_mfma<4,1,0,0,1><<<dim3(Mg/256, 1, 2), 256, 0, stream>>>(g2, 1024, 1024, 64, 1024);

        ScanPair spp = {};  // scan: seq-split P=2, 1024 rows per block
        spp.dblh[0] = dblh_f; spp.dblh[1] = dblh_b;
        spp.dtw[0] = wdtf;    spp.dtw[1] = wdtb;
        spp.dtb[0] = f_dtb;   spp.dtb[1] = b_dtb;
        spp.xiy[0] = xiy_f;   spp.xiy[1] = xiy_b;
        spp.dbl[0] = dbl_f;   spp.dbl[1] = dbl_b;
        spp.xz[0] = xz_f;     spp.xz[1] = xz_b;
        spp.Al[0] = f_Al;     spp.Al[1] = b_Al;
        spp.Dp[0] = f_Dp;     spp.Dp[1] = b_Dp;
        spp.cumg[0] = cum_f;  spp.cumg[1] = cum_b;
        spp.he[0] = he_f;     spp.he[1] = he_b;
        scan_k<<<dim3(32, G * 2, 2), 256, 0, stream>>>(spp);

        FixArgs fa = {};
        fa.cumg[0] = cum_f; fa.cumg[1] = cum_b;
        fa.he[0] = he_f;    fa.he[1] = he_b;
        fa.al2[0] = al2f;   fa.al2[1] = al2b;
        fa.dbl[0] = dbl_f;  fa.dbl[1] = dbl_b;
        fa.xz[0] = xz_f;    fa.xz[1] = xz_b;
        fa.xiy[0] = xiy_f;  fa.xiy[1] = xiy_b;
        fix_k<<<dim3(32, G * 4, 2), 256, 0, stream>>>(fa);

        // fused out-proj+final: out = [y_f | rev(y_b)] @ Wcomb^T + lin_b (K=2048)
        GemmPair g5 = {};
        g5.A[0] = xiy_f; g5.A2[0] = xiy_b; g5.W[0] = wcmb;
        g5.bias[0] = lin_b; g5.C[0] = outg;
        gemm_mfma<2,2,0,1024,0><<<dim3(Mg/128, 4, 1), 256, 0, stream>>>(g5, 1024, 2048, 512, 2048);
    }
}

// Round 5
// 760.993 us; speedup vs baseline: 1.2375x; 1.1933x over previous
//
#include <hip/hip_runtime.h>
#include <cmath>

#define LSEQ 2048
#define NBATCH 8

typedef __attribute__((ext_vector_type(8))) short short8;
typedef __attribute__((ext_vector_type(4))) float f32x4;
typedef __attribute__((ext_vector_type(2))) float f32x2;

__device__ __forceinline__ float silu_f(float x) {
    return x * __builtin_amdgcn_rcpf(1.0f + __expf(-x));
}
__device__ __forceinline__ float softplus_f(float x) {
    return fmaxf(x, 0.0f) + __logf(1.0f + __expf(-fabsf(x)));
}
__device__ __forceinline__ unsigned short f2bf(float f) {   // RNE fp32->bf16
    unsigned int u = __float_as_uint(f);
    u += 0x7FFFu + ((u >> 16) & 1u);
    return (unsigned short)(u >> 16);
}
__device__ __forceinline__ float bf2f(unsigned short h) {
    return __uint_as_float(((unsigned int)h) << 16);
}
__device__ __forceinline__ void gload_lds16(const void* g, void* l) {
    __builtin_amdgcn_global_load_lds((const __attribute__((address_space(1))) void*)g,
                                     (__attribute__((address_space(3))) void*)l, 16, 0, 0);
}

#if defined(__has_builtin)
#if __has_builtin(__builtin_amdgcn_exp2f)
#define EXP2F(x) __builtin_amdgcn_exp2f(x)
#endif
#endif
#ifndef EXP2F
#define EXP2F(x) __expf((x) * 0.69314718055994531f)
#endif

// fwd/bwd operand pairs; blockIdx.z selects direction
struct GemmPair {
    const unsigned short* A[2];
    const unsigned short* A2[2];   // DUAL second A (second K-half, row-reversed)
    const unsigned short* W[2];
    const float* bias[2];
    void* C[2];
    void* Cz[2];                   // SPLIT: cols >=1024 go here (ld = ldc)
    unsigned short* aux[2];
};

// ---------------------------------------------------------------------------
// bf16 MFMA GEMM (NT), r4-proven config: BK=32, scalar epilogue.
// SPLIT: N=2048 output split into two ld-1024 buffers (C: cols<1024, Cz: >=1024)
// ---------------------------------------------------------------------------
template<int WGM, int WGN, int OMODE, int DK, int XTRA, int SPLIT = 0>
__global__ __launch_bounds__(WGM* WGN * 64) void gemm_mfma(GemmPair gp, int lda, int ldw,
                                                           int ldc, int K)
{
    constexpr int NW = WGM * WGN;
    constexpr int TM = WGM * 64, TN = WGN * 64;
    __shared__ unsigned short As[TM * 32];
    __shared__ unsigned short Bs[TN * 32];
    const int dir = blockIdx.z;
    const unsigned short* A  = gp.A[dir];
    const unsigned short* A2 = gp.A2[dir];
    const unsigned short* W  = gp.W[dir];
    const float* bias        = gp.bias[dir];
    void* Cout               = gp.C[dir];
    void* Czout              = gp.Cz[dir];
    unsigned short* aux      = gp.aux[dir];

    const int tid = threadIdx.x;
    const int wave = tid >> 6, lane = tid & 63;
    const int wm = wave / WGN, wn = wave % WGN;
    const int m0 = blockIdx.x * TM, n0 = blockIdx.y * TN;
    const int l15 = lane & 15, l4 = lane >> 4;
    const int srow = lane >> 2, schunk = (lane & 3) * 8;

    f32x4 acc[4][4] = {};

    for (int k0 = 0; k0 < K; k0 += 32) {
        __syncthreads();
        for (int s = wave; s < TM / 16; s += NW) {
            const int gr = m0 + s * 16 + srow;
            const unsigned short* g;
            if (DK != 0 && k0 >= DK)
                g = A2 + (size_t)(gr ^ (LSEQ - 1)) * lda + (k0 - DK) + schunk;
            else
                g = A + (size_t)gr * lda + k0 + schunk;
            gload_lds16(g, (char*)As + (size_t)s * 1024);
        }
        for (int s = wave; s < TN / 16; s += NW) {
            const int gr = n0 + s * 16 + srow;
            const unsigned short* g = W + (size_t)gr * ldw + k0 + schunk;
            gload_lds16(g, (char*)Bs + (size_t)s * 1024);
        }
        __syncthreads();
        short8 af[4], bfr[4];
#pragma unroll
        for (int mi = 0; mi < 4; ++mi)
            af[mi] = *(const short8*)&As[(wm * 64 + mi * 16 + l15) * 32 + l4 * 8];
#pragma unroll
        for (int ni = 0; ni < 4; ++ni)
            bfr[ni] = *(const short8*)&Bs[(wn * 64 + ni * 16 + l15) * 32 + l4 * 8];
#pragma unroll
        for (int mi = 0; mi < 4; ++mi)
#pragma unroll
            for (int ni = 0; ni < 4; ++ni)
                acc[mi][ni] = __builtin_amdgcn_mfma_f32_16x16x32_bf16(af[mi], bfr[ni], acc[mi][ni], 0, 0, 0);
    }

    void* Cb = (SPLIT && blockIdx.y * TN >= 1024) ? Czout : Cout;
#pragma unroll
    for (int mi = 0; mi < 4; ++mi)
#pragma unroll
        for (int ni = 0; ni < 4; ++ni)
#pragma unroll
            for (int r = 0; r < 4; ++r) {
                const int row = m0 + wm * 64 + mi * 16 + l4 * 4 + r;
                const int col = n0 + wn * 64 + ni * 16 + l15;
                const int colL = SPLIT ? (col & 1023) : col;
                float v = acc[mi][ni][r];
                if (bias) v += bias[col];
                if (OMODE & 1) ((unsigned short*)Cb)[(size_t)row * ldc + colL] = f2bf(v);
                else           ((float*)Cb)[(size_t)row * ldc + colL] = v;
                if (XTRA) { if (col < 32) aux[(size_t)row * 32 + col] = f2bf(v); }
            }
}

// ---------------------------------------------------------------------------
// Combined weight for fused out-proj+final (proven r7: identical absmax):
// ---------------------------------------------------------------------------
__global__ __launch_bounds__(256) void combine_k(
    const float* __restrict__ lin_w, const float* __restrict__ owf,
    const float* __restrict__ owb, unsigned short* __restrict__ Wcomb)
{
    const int dir = blockIdx.z;
    const float* ow = dir ? owb : owf;
    const int lane = threadIdx.x & 63;
    const int wave = threadIdx.x >> 6;
    const int n = blockIdx.y * 4 + wave;          // 0..511
    const int d = blockIdx.x * 256 + lane * 4;    // 0..1023
    float4 acc = {0.f, 0.f, 0.f, 0.f};
    const float* lrow = lin_w + (size_t)n * 1024 + dir * 512;
    for (int j = 0; j < 512; ++j) {
        const float s = lrow[j];
        const float4 v = *(const float4*)&ow[(size_t)j * 1024 + d];
        acc.x = fmaf(s, v.x, acc.x); acc.y = fmaf(s, v.y, acc.y);
        acc.z = fmaf(s, v.z, acc.z); acc.w = fmaf(s, v.w, acc.w);
    }
    ushort4 o;
    o.x = f2bf(acc.x); o.y = f2bf(acc.y); o.z = f2bf(acc.z); o.w = f2bf(acc.w);
    *(ushort4*)&Wcomb[(size_t)n * 2048 + dir * 1024 + d] = o;
}

// ---------------------------------------------------------------------------
// fp32 -> bf16 conversion: 6 weight segments, one launch.
// ---------------------------------------------------------------------------
struct CvtArgs { const float* s[6]; unsigned short* d[6]; int n[6]; };
__global__ __launch_bounds__(256) void cvt_k(CvtArgs a)
{
    const int sid = blockIdx.y;
    const float* s = a.s[sid];
    unsigned short* d = a.d[sid];
    const int n4 = a.n[sid] >> 2;
    for (int i = blockIdx.x * 256 + threadIdx.x; i < n4; i += gridDim.x * 256) {
        const float4 v = ((const float4*)s)[i];
        ushort4 o; o.x = f2bf(v.x); o.y = f2bf(v.y); o.z = f2bf(v.z); o.w = f2bf(v.w);
        ((ushort4*)d)[i] = o;
    }
}
__global__ __launch_bounds__(256) void cvtx_k(const float* __restrict__ s,
                                              unsigned short* __restrict__ d, int n4)
{
    for (int i = blockIdx.x * 256 + threadIdx.x; i < n4; i += gridDim.x * 256) {
        const float4 v = ((const float4*)s)[i];
        ushort4 o; o.x = f2bf(v.x); o.y = f2bf(v.y); o.z = f2bf(v.z); o.w = f2bf(v.w);
        ((ushort4*)d)[i] = o;
    }
}

// A_log -> -exp(A_log)*log2(e) tables for both dirs (used by fix_k)
__global__ __launch_bounds__(256) void alprep_k(const float* __restrict__ af,
                                                const float* __restrict__ ab,
                                                float* __restrict__ of,
                                                float* __restrict__ ob)
{
    const int i = blockIdx.x * 256 + threadIdx.x;
    if (i < 16384) {
        of[i] = -expf(af[i]) * 1.4426950408889634f;
        ob[i] = -expf(ab[i]) * 1.4426950408889634f;
    }
}

// ---------------------------------------------------------------------------
// Causal depthwise conv(4) + bias + SiLU, both dirs; reads xc (ld 1024).
// ---------------------------------------------------------------------------
__global__ __launch_bounds__(256) void conv_silu_k(
    const unsigned short* __restrict__ xc_f, const float* __restrict__ cw_f,
    const float* __restrict__ cb_f, unsigned short* __restrict__ xi_f,
    const unsigned short* __restrict__ xc_b, const float* __restrict__ cw_b,
    const float* __restrict__ cb_b, unsigned short* __restrict__ xi_b)
{
    const int dir = blockIdx.y;
    const unsigned short* xc = dir ? xc_b : xc_f;
    const float* cw = dir ? cw_b : cw_f;
    const float* cb = dir ? cb_b : cb_f;
    unsigned short* xi = dir ? xi_b : xi_f;

    const int bt = blockIdx.x;
    const int b = bt >> 11;
    const int t = bt & (LSEQ - 1);
    const int d = threadIdx.x << 2;

    float w[4][4];
#pragma unroll
    for (int i = 0; i < 4; ++i) {
        const float4 wr = *(const float4*)&cw[(d + i) * 4];
        w[i][0] = wr.x; w[i][1] = wr.y; w[i][2] = wr.z; w[i][3] = wr.w;
    }
    float4 acc = *(const float4*)&cb[d];
#pragma unroll
    for (int k = 0; k < 4; ++k) {
        const int row = dir ? (LSEQ - 1 - t) + 3 - k : t - 3 + k;
        if ((unsigned)row < (unsigned)LSEQ) {
            const ushort4 v = *(const ushort4*)&xc[(size_t)(b * LSEQ + row) * 1024 + d];
            acc.x += w[0][k] * bf2f(v.x); acc.y += w[1][k] * bf2f(v.y);
            acc.z += w[2][k] * bf2f(v.z); acc.w += w[3][k] * bf2f(v.w);
        }
    }
    ushort4 st;
    st.x = f2bf(silu_f(acc.x)); st.y = f2bf(silu_f(acc.y));
    st.z = f2bf(silu_f(acc.z)); st.w = f2bf(silu_f(acc.w));
    *(ushort4*)&xi[(size_t)(b * LSEQ + t) * 1024 + d] = st;
}

// ---------------------------------------------------------------------------
// Selective scan, seq-split P=2 (round 5):
//  - part 0: full scan + gated epilogue + h_end (he).
//  - part 1: local scan from h=0; raw y+xi*Dp bf16 in-place into xiy; cum
//    f32 -> cumg (ALIASED onto dead xc buffer -> perRow back to 13952, G=8).
//  - z read from dedicated zb buffer (ld 1024).
//  - h chains packed as f32x2 (v_pk_fma_f32 candidate).
// ---------------------------------------------------------------------------
__device__ __forceinline__ float row_sum8(float x) {
    x += __int_as_float(__builtin_amdgcn_update_dpp(0, __float_as_int(x), 0xB1, 0xF, 0xF, true));  // quad xor1
    x += __int_as_float(__builtin_amdgcn_update_dpp(0, __float_as_int(x), 0x4E, 0xF, 0xF, true));  // quad xor2
    x += __int_as_float(__builtin_amdgcn_update_dpp(0, __float_as_int(x), 0x141, 0xF, 0xF, true)); // row_half_mirror
    return x;
}

struct ScanPair {
    const unsigned short* dblh[2];   // (rows x 32) bf16
    const unsigned short* dtw[2];    // (1024 x 32) bf16
    const float* dtb[2];             // (1024) f32
    unsigned short* xiy[2];          // (rows x 1024) bf16, in/out
    const float* dbl[2];             // (rows x 64) f32, B/C in cols 32..63
    const unsigned short* zb[2];     // (rows x 1024) bf16, z
    const float* Al[2];
    const float* Dp[2];
    float* cumg[2];                  // (G*1024 x 1024) f32: part-1 cumsum(dt)
    float* he[2];                    // (G*1024 x 16) f32: part-0 h_end
};

__global__ __launch_bounds__(256, 3) void scan_k(ScanPair sp)
{
    __shared__ unsigned short sxi[64][40];       // [t][ch] raw bf16
    __shared__ float sdt[32][68], sdtx[32][68];  // [ch][t]
    __shared__ float sB2[8][140], sC2[8][140];   // [np][t*2+half]: {B_np, B_np+8}
    __shared__ float sy[32][68];                 // [ch][t]
    __shared__ float scum[32][68];               // [ch][t] (part 1 only)

    const int dir = blockIdx.z;
    const unsigned short* dblh = sp.dblh[dir];
    const unsigned short* dtw  = sp.dtw[dir];
    const float* dtb           = sp.dtb[dir];
    unsigned short* xiy        = sp.xiy[dir];
    const float* dbl           = sp.dbl[dir];
    const unsigned short* zz   = sp.zb[dir];
    const float* Al            = sp.Al[dir];
    const float* Dpp           = sp.Dp[dir];
    float* cumg                = sp.cumg[dir];
    float* hep                 = sp.he[dir];

    const int by = blockIdx.y;
    const int b = by >> 1, part = by & 1;
    const int rbase = b * LSEQ + part * (LSEQ / 2);
    const int d0 = blockIdx.x << 5;
    const int tid = threadIdx.x;
    const int wave = tid >> 6, lane = tid & 63;
    const int l15 = lane & 15, l4 = lane >> 4;
    const int di = tid >> 3, np = tid & 7;     // inner-loop mapping
    const int lr = tid >> 2, lc = tid & 3;     // stage/epilogue mapping
    const bool lead = (np == 0);

    // A constants pre-scaled by log2(e) so exp2 needs no extra mul
    const f32x2 ALv = {-expf(Al[(d0 + di) * 16 + np]) * 1.4426950408889634f,
                       -expf(Al[(d0 + di) * 16 + np + 8]) * 1.4426950408889634f};

    // dt MFMA B-fragments: rows = the block's 32 channels (two 16-ch halves)
    const short8 dtwf0 = *(const short8*)&dtw[(size_t)(d0 + l15) * 32 + l4 * 8];
    const short8 dtwf1 = *(const short8*)&dtw[(size_t)(d0 + 16 + l15) * 32 + l4 * 8];
    const float dtb0 = dtb[d0 + l15], dtb1 = dtb[d0 + 16 + l15];

    float dpv[8];
#pragma unroll
    for (int i = 0; i < 8; ++i) dpv[i] = Dpp[d0 + lc * 8 + i];

    ushort4 pxi0, pxi1;
    float4 pB, pC;
    short8 pA;
    auto issue_loads = [&](int c) {
        const size_t r = (size_t)rbase + c * 64 + lr;
        pxi0 = *(const ushort4*)&xiy[r * 1024 + d0 + lc * 8];
        pxi1 = *(const ushort4*)&xiy[r * 1024 + d0 + lc * 8 + 4];
        pB   = *(const float4*)&dbl[r * 64 + 32 + lc * 4];
        pC   = *(const float4*)&dbl[r * 64 + 48 + lc * 4];
        // dt MFMA A-fragment: rows = this wave's 16 timesteps of the chunk
        pA   = *(const short8*)&dblh[(size_t)(rbase + c * 64 + wave * 16 + l15) * 32 + l4 * 8];
    };
    issue_loads(0);

    constexpr int NT = (LSEQ / 2) / 64;   // 16 chunks per partition
    f32x2 h = {0.f, 0.f};
    float cum = 0.0f;
    for (int c = 0; c < NT; ++c) {
        const int t0 = c * 64;
        // ---- stage xi raw bf16 [t][ch] and B/C pairs ----
        *(ushort4*)&sxi[lr][lc * 8]     = pxi0;
        *(ushort4*)&sxi[lr][lc * 8 + 4] = pxi1;
        {
            const float bv[4] = {pB.x, pB.y, pB.z, pB.w};
            const float cv[4] = {pC.x, pC.y, pC.z, pC.w};
#pragma unroll
            for (int i = 0; i < 4; ++i) {
                const int n = lc * 4 + i;
                sB2[n & 7][lr * 2 + (n >> 3)] = bv[i];
                sC2[n & 7][lr * 2 + (n >> 3)] = cv[i];
            }
        }
        __syncthreads();   // barC-pre: stage visible to all
        // ---- dt phase: MFMA -> softplus -> sdt, and dtx = dt*xi -> sdtx ----
        {
            f32x4 z4 = {0.f, 0.f, 0.f, 0.f};
            f32x4 dacc0 = __builtin_amdgcn_mfma_f32_16x16x32_bf16(pA, dtwf0, z4, 0, 0, 0);
            f32x4 dacc1 = __builtin_amdgcn_mfma_f32_16x16x32_bf16(pA, dtwf1, z4, 0, 0, 0);
            const int tq = wave * 16 + l4 * 4;
            float4 xi0, xi1;
            xi0.x = bf2f(sxi[tq + 0][l15]);      xi0.y = bf2f(sxi[tq + 1][l15]);
            xi0.z = bf2f(sxi[tq + 2][l15]);      xi0.w = bf2f(sxi[tq + 3][l15]);
            xi1.x = bf2f(sxi[tq + 0][16 + l15]); xi1.y = bf2f(sxi[tq + 1][16 + l15]);
            xi1.z = bf2f(sxi[tq + 2][16 + l15]); xi1.w = bf2f(sxi[tq + 3][16 + l15]);
            float4 dv0, dv1, dx0, dx1;
            dv0.x = softplus_f(dacc0[0] + dtb0); dv0.y = softplus_f(dacc0[1] + dtb0);
            dv0.z = softplus_f(dacc0[2] + dtb0); dv0.w = softplus_f(dacc0[3] + dtb0);
            dv1.x = softplus_f(dacc1[0] + dtb1); dv1.y = softplus_f(dacc1[1] + dtb1);
            dv1.z = softplus_f(dacc1[2] + dtb1); dv1.w = softplus_f(dacc1[3] + dtb1);
            dx0.x = dv0.x * xi0.x; dx0.y = dv0.y * xi0.y;
            dx0.z = dv0.z * xi0.z; dx0.w = dv0.w * xi0.w;
            dx1.x = dv1.x * xi1.x; dx1.y = dv1.y * xi1.y;
            dx1.z = dv1.z * xi1.z; dx1.w = dv1.w * xi1.w;
            *(float4*)&sdt[l15][tq]       = dv0;
            *(float4*)&sdt[16 + l15][tq]  = dv1;
            *(float4*)&sdtx[l15][tq]      = dx0;
            *(float4*)&sdtx[16 + l15][tq] = dx1;
        }
        const ushort4 oxi0 = pxi0, oxi1 = pxi1;
        ushort4 pz0 = {}, pz1 = {};
        if (part == 0) {
            const int tg = t0 + lr;
            const int tz = dir ? (LSEQ - 1 - tg) : tg;
            pz0 = *(const ushort4*)&zz[((size_t)b * LSEQ + tz) * 1024 + d0 + lc * 8];
            pz1 = *(const ushort4*)&zz[((size_t)b * LSEQ + tz) * 1024 + d0 + lc * 8 + 4];
        }
        if (c + 1 < NT) issue_loads(c + 1);
        __syncthreads();   // barC: sdt/sdtx visible, inner may start
        // ---- inner scan: 64 timesteps, 2 states per thread (f32x2 packed) ----
#pragma unroll 4
        for (int tt = 0; tt < 64; tt += 4) {
            const float4 d4 = *(const float4*)&sdt[di][tt];
            const float4 u4 = *(const float4*)&sdtx[di][tt];
            const float4 bA = *(const float4*)&sB2[np][tt * 2];
            const float4 bB = *(const float4*)&sB2[np][tt * 2 + 4];
            const float4 cA = *(const float4*)&sC2[np][tt * 2];
            const float4 cB = *(const float4*)&sC2[np][tt * 2 + 4];
            float4 ppv;
            {
                f32x2 e = ALv * d4.x;
                e.x = EXP2F(e.x); e.y = EXP2F(e.y);
                const f32x2 b2 = {bA.x, bA.y};
                const f32x2 c2 = {cA.x, cA.y};
                h = e * h + b2 * u4.x;
                const f32x2 pc = h * c2;
                ppv.x = row_sum8(pc.x + pc.y);
            }
            {
                f32x2 e = ALv * d4.y;
                e.x = EXP2F(e.x); e.y = EXP2F(e.y);
                const f32x2 b2 = {bA.z, bA.w};
                const f32x2 c2 = {cA.z, cA.w};
                h = e * h + b2 * u4.y;
                const f32x2 pc = h * c2;
                ppv.y = row_sum8(pc.x + pc.y);
            }
            {
                f32x2 e = ALv * d4.z;
                e.x = EXP2F(e.x); e.y = EXP2F(e.y);
                const f32x2 b2 = {bB.x, bB.y};
                const f32x2 c2 = {cB.x, cB.y};
                h = e * h + b2 * u4.z;
                const f32x2 pc = h * c2;
                ppv.z = row_sum8(pc.x + pc.y);
            }
            {
                f32x2 e = ALv * d4.w;
                e.x = EXP2F(e.x); e.y = EXP2F(e.y);
                const f32x2 b2 = {bB.z, bB.w};
                const f32x2 c2 = {cB.z, cB.w};
                h = e * h + b2 * u4.w;
                const f32x2 pc = h * c2;
                ppv.w = row_sum8(pc.x + pc.y);
            }
            if (part) {
                const float c0 = cum + d4.x, c1 = c0 + d4.y;
                const float c2s = c1 + d4.z, c3 = c2s + d4.w;
                cum = c3;
                if (lead) {
                    float4 cc; cc.x = c0; cc.y = c1; cc.z = c2s; cc.w = c3;
                    *(float4*)&scum[di][tt] = cc;
                }
            }
            if (lead) *(float4*)&sy[di][tt] = ppv;
        }
        __syncthreads();   // barD: sy/scum complete; staging arrays free
        // ---- epilogue ----
        if (part == 0) {
            const size_t r = (size_t)rbase + t0 + lr;
            ushort4 s0, s1;
            s0.x = f2bf(fmaf(bf2f(oxi0.x), dpv[0], sy[lc * 8 + 0][lr]) * silu_f(bf2f(pz0.x)));
            s0.y = f2bf(fmaf(bf2f(oxi0.y), dpv[1], sy[lc * 8 + 1][lr]) * silu_f(bf2f(pz0.y)));
            s0.z = f2bf(fmaf(bf2f(oxi0.z), dpv[2], sy[lc * 8 + 2][lr]) * silu_f(bf2f(pz0.z)));
            s0.w = f2bf(fmaf(bf2f(oxi0.w), dpv[3], sy[lc * 8 + 3][lr]) * silu_f(bf2f(pz0.w)));
            s1.x = f2bf(fmaf(bf2f(oxi1.x), dpv[4], sy[lc * 8 + 4][lr]) * silu_f(bf2f(pz1.x)));
            s1.y = f2bf(fmaf(bf2f(oxi1.y), dpv[5], sy[lc * 8 + 5][lr]) * silu_f(bf2f(pz1.y)));
            s1.z = f2bf(fmaf(bf2f(oxi1.z), dpv[6], sy[lc * 8 + 6][lr]) * silu_f(bf2f(pz1.z)));
            s1.w = f2bf(fmaf(bf2f(oxi1.w), dpv[7], sy[lc * 8 + 7][lr]) * silu_f(bf2f(pz1.w)));
            *(ushort4*)&xiy[r * 1024 + d0 + lc * 8] = s0;
            *(ushort4*)&xiy[r * 1024 + d0 + lc * 8 + 4] = s1;
        } else {
            // raw y + xi*Dp as bf16 in place; cum coalesced f32
            const size_t r = (size_t)rbase + t0 + lr;
            ushort4 s0, s1;
            s0.x = f2bf(fmaf(bf2f(oxi0.x), dpv[0], sy[lc * 8 + 0][lr]));
            s0.y = f2bf(fmaf(bf2f(oxi0.y), dpv[1], sy[lc * 8 + 1][lr]));
            s0.z = f2bf(fmaf(bf2f(oxi0.z), dpv[2], sy[lc * 8 + 2][lr]));
            s0.w = f2bf(fmaf(bf2f(oxi0.w), dpv[3], sy[lc * 8 + 3][lr]));
            s1.x = f2bf(fmaf(bf2f(oxi1.x), dpv[4], sy[lc * 8 + 4][lr]));
            s1.y = f2bf(fmaf(bf2f(oxi1.y), dpv[5], sy[lc * 8 + 5][lr]));
            s1.z = f2bf(fmaf(bf2f(oxi1.z), dpv[6], sy[lc * 8 + 6][lr]));
            s1.w = f2bf(fmaf(bf2f(oxi1.w), dpv[7], sy[lc * 8 + 7][lr]));
            *(ushort4*)&xiy[r * 1024 + d0 + lc * 8] = s0;
            *(ushort4*)&xiy[r * 1024 + d0 + lc * 8 + 4] = s1;
            float4 c0v, c1v;
            c0v.x = scum[lc * 8 + 0][lr]; c0v.y = scum[lc * 8 + 1][lr];
            c0v.z = scum[lc * 8 + 2][lr]; c0v.w = scum[lc * 8 + 3][lr];
            c1v.x = scum[lc * 8 + 4][lr]; c1v.y = scum[lc * 8 + 5][lr];
            c1v.z = scum[lc * 8 + 6][lr]; c1v.w = scum[lc * 8 + 7][lr];
            const size_t pr = (size_t)(b * (LSEQ / 2) + t0 + lr) * 1024 + d0 + lc * 8;
            *(float4*)&cumg[pr]     = c0v;
            *(float4*)&cumg[pr + 4] = c1v;
        }
    }
    if (part == 0) {
        float* hh = &hep[((size_t)b * 1024 + d0 + di) * 16 + np];
        hh[0] = h.x; hh[8] = h.y;
    }
}

// ---------------------------------------------------------------------------
// Part-1 fixup: block = 32 ch x 256 t-quarter x batch; AL/HE/C staged ONCE
// in LDS, loop over 32 iterations of 8 t. In-place on xiy.
// ---------------------------------------------------------------------------
struct FixArgs {
    const float* cumg[2]; const float* he[2]; const float* al2[2];
    const float* dbl[2];  const unsigned short* zb[2]; unsigned short* xiy[2];
};
__global__ __launch_bounds__(256) void fix_k(FixArgs a)
{
    const int dir = blockIdx.z;
    const float* cumg          = a.cumg[dir];
    const float* he            = a.he[dir];
    const float* al2           = a.al2[dir];
    const float* dbl           = a.dbl[dir];
    const unsigned short* zz   = a.zb[dir];
    unsigned short* xiy        = a.xiy[dir];

    __shared__ float sAL[32][17], sHE[32][17];
    __shared__ float sCt[256][16];

    const int tid = threadIdx.x;
    const int d0 = blockIdx.x << 5;           // 32-ch block
    const int by = blockIdx.y;
    const int b = by >> 2, q = by & 3;        // quarter (256 t) of part 1
    const int tq0 = q << 8;

    for (int i = tid; i < 512; i += 256) {
        const int dd = i >> 4, nn = i & 15;
        sAL[dd][nn] = al2[(size_t)(d0 + dd) * 16 + nn];
        sHE[dd][nn] = he[((size_t)b * 1024 + d0 + dd) * 16 + nn];
    }
    for (int i = tid; i < 4096; i += 256) {
        const int tt = i >> 4, nn = i & 15;
        sCt[tt][nn] = dbl[((size_t)b * LSEQ + (LSEQ / 2) + tq0 + tt) * 64 + 48 + nn];
    }
    __syncthreads();

    const int ts = tid >> 5, dd = tid & 31;
    for (int it = 0; it < 32; ++it) {
        const int tl = tq0 + it * 8 + ts;                 // part-local t
        const int tglob = (LSEQ / 2) + tl;
        const size_t grow = (size_t)b * LSEQ + tglob;
        const float cv = cumg[((size_t)b * (LSEQ / 2) + tl) * 1024 + d0 + dd];
        const float yv0 = bf2f(xiy[grow * 1024 + d0 + dd]);
        const int tz = dir ? (LSEQ - 1 - tglob) : tglob;
        const float z = bf2f(zz[((size_t)b * LSEQ + tz) * 1024 + d0 + dd]);
        float corr = 0.f;
#pragma unroll
        for (int n = 0; n < 16; ++n)
            corr = fmaf(sCt[it * 8 + ts][n] * sHE[dd][n], EXP2F(sAL[dd][n] * cv), corr);
        xiy[grow * 1024 + d0 + dd] = f2bf((yv0 + corr) * silu_f(z));
    }
}

// ---------------------------------------------------------------------------
extern "C" void kernel_launch(void* const* d_in, const int* in_sizes, int n_in,
                              void* d_out, int out_size, void* d_ws, size_t ws_size,
                              hipStream_t stream)
{
    const float* x      = (const float*)d_in[0];
    const float* f_in_w = (const float*)d_in[1];
    const float* f_cw   = (const float*)d_in[2];
    const float* f_cb   = (const float*)d_in[3];
    const float* f_xp   = (const float*)d_in[4];
    const float* f_dtw  = (const float*)d_in[5];
    const float* f_dtb  = (const float*)d_in[6];
    const float* f_Al   = (const float*)d_in[7];
    const float* f_Dp   = (const float*)d_in[8];
    const float* f_ow   = (const float*)d_in[9];
    const float* b_in_w = (const float*)d_in[10];
    const float* b_cw   = (const float*)d_in[11];
    const float* b_cb   = (const float*)d_in[12];
    const float* b_xp   = (const float*)d_in[13];
    const float* b_dtw  = (const float*)d_in[14];
    const float* b_dtb  = (const float*)d_in[15];
    const float* b_Al   = (const float*)d_in[16];
    const float* b_Dp   = (const float*)d_in[17];
    const float* b_ow   = (const float*)d_in[18];
    const float* lin_w  = (const float*)d_in[19];
    const float* lin_b  = (const float*)d_in[20];
    float* out = (float*)d_out;

    char* p = (char*)d_ws;
    auto take = [&](size_t bytes) -> char* {
        char* r = p; p += (bytes + 255) & ~(size_t)255; return r;
    };

    // persistent bf16 weights + AL2 tables
    unsigned short* wif  = (unsigned short*)take((size_t)2048 * 512 * 2);
    unsigned short* wib  = (unsigned short*)take((size_t)2048 * 512 * 2);
    unsigned short* wxf  = (unsigned short*)take((size_t)64 * 1024 * 2);
    unsigned short* wxb  = (unsigned short*)take((size_t)64 * 1024 * 2);
    unsigned short* wdtf = (unsigned short*)take((size_t)1024 * 32 * 2);
    unsigned short* wdtb = (unsigned short*)take((size_t)1024 * 32 * 2);
    unsigned short* wcmb = (unsigned short*)take((size_t)512 * 2048 * 2);
    float* al2f = (float*)take((size_t)1024 * 16 * 4);
    float* al2b = (float*)take((size_t)1024 * 16 * 4);

    const size_t used = (size_t)(p - (char*)d_ws);
    // per-row bytes: xbf 1024 + per dir (xc 2048 + zb 2048 + xiy 2048 + dbl 256
    //                                    + dblh 64); cum ALIASED onto xc.
    const size_t perRow = 1024 + 2 * (2048 + 2048 + 2048 + 256 + 64);
    int G = 1;
    for (int g = 8; g >= 1; g >>= 1) {
        const size_t need = used + (size_t)g * LSEQ * perRow + (size_t)g * 2 * 1024 * 16 * 4 + 16384;
        if (need <= ws_size || g == 1) { G = g; break; }
    }

    CvtArgs ca;
    ca.s[0] = f_in_w; ca.d[0] = wif;  ca.n[0] = 2048 * 512;
    ca.s[1] = b_in_w; ca.d[1] = wib;  ca.n[1] = 2048 * 512;
    ca.s[2] = f_xp;   ca.d[2] = wxf;  ca.n[2] = 64 * 1024;
    ca.s[3] = b_xp;   ca.d[3] = wxb;  ca.n[3] = 64 * 1024;
    ca.s[4] = f_dtw;  ca.d[4] = wdtf; ca.n[4] = 1024 * 32;
    ca.s[5] = b_dtw;  ca.d[5] = wdtb; ca.n[5] = 1024 * 32;
    cvt_k<<<dim3(128, 6), 256, 0, stream>>>(ca);

    alprep_k<<<dim3(64), 256, 0, stream>>>(f_Al, b_Al, al2f, al2b);

    // combined (lin_w @ out_w) weight, bf16, (512 x 2048) — proven r7
    combine_k<<<dim3(4, 128, 2), 256, 0, stream>>>(lin_w, f_ow, b_ow, wcmb);

    char* pg0 = p;
    for (int g0 = 0; g0 < NBATCH; g0 += G) {
        const int Mg = G * LSEQ;
        p = pg0;
        unsigned short* xbf   = (unsigned short*)take((size_t)Mg * 512 * 2);
        unsigned short* xc_f  = (unsigned short*)take((size_t)Mg * 1024 * 2);
        unsigned short* zb_f  = (unsigned short*)take((size_t)Mg * 1024 * 2);
        unsigned short* xc_b  = (unsigned short*)take((size_t)Mg * 1024 * 2);
        unsigned short* zb_b  = (unsigned short*)take((size_t)Mg * 1024 * 2);
        unsigned short* xiy_f = (unsigned short*)take((size_t)Mg * 1024 * 2);
        unsigned short* xiy_b = (unsigned short*)take((size_t)Mg * 1024 * 2);
        float* dbl_f          = (float*)take((size_t)Mg * 64 * 4);
        float* dbl_b          = (float*)take((size_t)Mg * 64 * 4);
        unsigned short* dblh_f= (unsigned short*)take((size_t)Mg * 32 * 2);
        unsigned short* dblh_b= (unsigned short*)take((size_t)Mg * 32 * 2);
        float* he_f           = (float*)take((size_t)G * 1024 * 16 * 4);
        float* he_b           = (float*)take((size_t)G * 1024 * 16 * 4);
        // cum aliased onto dead conv-input buffers (exact size match)
        float* cum_f = (float*)xc_f;
        float* cum_b = (float*)xc_b;

        const float* xg = x + (size_t)g0 * LSEQ * 512;
        float* outg = out + (size_t)g0 * LSEQ * 512;

        cvtx_k<<<dim3(512), 256, 0, stream>>>(xg, xbf, Mg * 512 / 4);

        GemmPair g1 = {};   // in-proj: split output xc (cols<1024) / zb (>=1024)
        g1.A[0] = xbf; g1.A[1] = xbf; g1.W[0] = wif; g1.W[1] = wib;
        g1.C[0] = xc_f; g1.C[1] = xc_b; g1.Cz[0] = zb_f; g1.Cz[1] = zb_b;
        gemm_mfma<2,2,1,0,0,1><<<dim3(Mg/128, 16, 2), 256, 0, stream>>>(g1, 512, 512, 1024, 512);

        conv_silu_k<<<dim3(Mg, 2), 256, 0, stream>>>(xc_f, f_cw, f_cb, xiy_f,
                                                     xc_b, b_cw, b_cb, xiy_b);

        GemmPair g2 = {};   // x-proj: dbl f32 (ldc 64) + bf16 cols<32 (dblh)
        g2.A[0] = xiy_f; g2.A[1] = xiy_b; g2.W[0] = wxf; g2.W[1] = wxb;
        g2.C[0] = dbl_f; g2.C[1] = dbl_b; g2.aux[0] = dblh_f; g2.aux[1] = dblh_b;
        gemm_mfma<4,1,0,0,1><<<dim3(Mg/256, 1, 2), 256, 0, stream>>>(g2, 1024, 1024, 64, 1024);

        ScanPair spp = {};  // scan: seq-split P=2, 1024 rows per block
        spp.dblh[0] = dblh_f; spp.dblh[1] = dblh_b;
        spp.dtw[0] = wdtf;    spp.dtw[1] = wdtb;
        spp.dtb[0] = f_dtb;   spp.dtb[1] = b_dtb;
        spp.xiy[0] = xiy_f;   spp.xiy[1] = xiy_b;
        spp.dbl[0] = dbl_f;   spp.dbl[1] = dbl_b;
        spp.zb[0] = zb_f;     spp.zb[1] = zb_b;
        spp.Al[0] = f_Al;     spp.Al[1] = b_Al;
        spp.Dp[0] = f_Dp;     spp.Dp[1] = b_Dp;
        spp.cumg[0] = cum_f;  spp.cumg[1] = cum_b;
        spp.he[0] = he_f;     spp.he[1] = he_b;
        scan_k<<<dim3(32, G * 2, 2), 256, 0, stream>>>(spp);

        FixArgs fa = {};
        fa.cumg[0] = cum_f; fa.cumg[1] = cum_b;
        fa.he[0] = he_f;    fa.he[1] = he_b;
        fa.al2[0] = al2f;   fa.al2[1] = al2b;
        fa.dbl[0] = dbl_f;  fa.dbl[1] = dbl_b;
        fa.zb[0] = zb_f;    fa.zb[1] = zb_b;
        fa.xiy[0] = xiy_f;  fa.xiy[1] = xiy_b;
        fix_k<<<dim3(32, G * 4, 2), 256, 0, stream>>>(fa);

        // fused out-proj+final: out = [y_f | rev(y_b)] @ Wcomb^T + lin_b (K=2048)
        GemmPair g5 = {};
        g5.A[0] = xiy_f; g5.A2[0] = xiy_b; g5.W[0] = wcmb;
        g5.bias[0] = lin_b; g5.C[0] = outg;
        gemm_mfma<2,2,0,1024,0><<<dim3(Mg/128, 4, 1), 256, 0, stream>>>(g5, 1024, 2048, 512, 2048);
    }
}

// Round 6
// 682.251 us; speedup vs baseline: 1.3804x; 1.1154x over previous
//
#include <hip/hip_runtime.h>
#include <cmath>

#define LSEQ 2048
#define NBATCH 8

typedef __attribute__((ext_vector_type(8))) short short8;
typedef __attribute__((ext_vector_type(4))) float f32x4;
typedef __attribute__((ext_vector_type(2))) float f32x2;

__device__ __forceinline__ float silu_f(float x) {
    return x * __builtin_amdgcn_rcpf(1.0f + __expf(-x));
}
__device__ __forceinline__ float softplus_f(float x) {
    return fmaxf(x, 0.0f) + __logf(1.0f + __expf(-fabsf(x)));
}
__device__ __forceinline__ unsigned short f2bf(float f) {   // RNE fp32->bf16
    unsigned int u = __float_as_uint(f);
    u += 0x7FFFu + ((u >> 16) & 1u);
    return (unsigned short)(u >> 16);
}
__device__ __forceinline__ float bf2f(unsigned short h) {
    return __uint_as_float(((unsigned int)h) << 16);
}
__device__ __forceinline__ void gload_lds16(const void* g, void* l) {
    __builtin_amdgcn_global_load_lds((const __attribute__((address_space(1))) void*)g,
                                     (__attribute__((address_space(3))) void*)l, 16, 0, 0);
}

#if defined(__has_builtin)
#if __has_builtin(__builtin_amdgcn_exp2f)
#define EXP2F(x) __builtin_amdgcn_exp2f(x)
#endif
#endif
#ifndef EXP2F
#define EXP2F(x) __expf((x) * 0.69314718055994531f)
#endif

// fwd/bwd operand pairs; blockIdx.z selects direction
struct GemmPair {
    const unsigned short* A[2];
    const unsigned short* A2[2];   // DUAL second A (second K-half, row-reversed)
    const unsigned short* W[2];
    const float* bias[2];
    void* C[2];
    void* Cz[2];                   // SPLIT: cols >=1024 go here (ld = ldc)
    unsigned short* aux[2];
};

// ---------------------------------------------------------------------------
// bf16 MFMA GEMM (NT), r4-proven config: BK=32, scalar epilogue.
// SPLIT: N=2048 output split into two ld-1024 buffers (C: cols<1024, Cz: >=1024)
// ---------------------------------------------------------------------------
template<int WGM, int WGN, int OMODE, int DK, int XTRA, int SPLIT = 0>
__global__ __launch_bounds__(WGM* WGN * 64) void gemm_mfma(GemmPair gp, int lda, int ldw,
                                                           int ldc, int K)
{
    constexpr int NW = WGM * WGN;
    constexpr int TM = WGM * 64, TN = WGN * 64;
    __shared__ unsigned short As[TM * 32];
    __shared__ unsigned short Bs[TN * 32];
    const int dir = blockIdx.z;
    const unsigned short* A  = gp.A[dir];
    const unsigned short* A2 = gp.A2[dir];
    const unsigned short* W  = gp.W[dir];
    const float* bias        = gp.bias[dir];
    void* Cout               = gp.C[dir];
    void* Czout              = gp.Cz[dir];
    unsigned short* aux      = gp.aux[dir];

    const int tid = threadIdx.x;
    const int wave = tid >> 6, lane = tid & 63;
    const int wm = wave / WGN, wn = wave % WGN;
    const int m0 = blockIdx.x * TM, n0 = blockIdx.y * TN;
    const int l15 = lane & 15, l4 = lane >> 4;
    const int srow = lane >> 2, schunk = (lane & 3) * 8;

    f32x4 acc[4][4] = {};

    for (int k0 = 0; k0 < K; k0 += 32) {
        __syncthreads();
        for (int s = wave; s < TM / 16; s += NW) {
            const int gr = m0 + s * 16 + srow;
            const unsigned short* g;
            if (DK != 0 && k0 >= DK)
                g = A2 + (size_t)(gr ^ (LSEQ - 1)) * lda + (k0 - DK) + schunk;
            else
                g = A + (size_t)gr * lda + k0 + schunk;
            gload_lds16(g, (char*)As + (size_t)s * 1024);
        }
        for (int s = wave; s < TN / 16; s += NW) {
            const int gr = n0 + s * 16 + srow;
            const unsigned short* g = W + (size_t)gr * ldw + k0 + schunk;
            gload_lds16(g, (char*)Bs + (size_t)s * 1024);
        }
        __syncthreads();
        short8 af[4], bfr[4];
#pragma unroll
        for (int mi = 0; mi < 4; ++mi)
            af[mi] = *(const short8*)&As[(wm * 64 + mi * 16 + l15) * 32 + l4 * 8];
#pragma unroll
        for (int ni = 0; ni < 4; ++ni)
            bfr[ni] = *(const short8*)&Bs[(wn * 64 + ni * 16 + l15) * 32 + l4 * 8];
#pragma unroll
        for (int mi = 0; mi < 4; ++mi)
#pragma unroll
            for (int ni = 0; ni < 4; ++ni)
                acc[mi][ni] = __builtin_amdgcn_mfma_f32_16x16x32_bf16(af[mi], bfr[ni], acc[mi][ni], 0, 0, 0);
    }

    void* Cb = (SPLIT && blockIdx.y * TN >= 1024) ? Czout : Cout;
#pragma unroll
    for (int mi = 0; mi < 4; ++mi)
#pragma unroll
        for (int ni = 0; ni < 4; ++ni)
#pragma unroll
            for (int r = 0; r < 4; ++r) {
                const int row = m0 + wm * 64 + mi * 16 + l4 * 4 + r;
                const int col = n0 + wn * 64 + ni * 16 + l15;
                const int colL = SPLIT ? (col & 1023) : col;
                float v = acc[mi][ni][r];
                if (bias) v += bias[col];
                if (OMODE & 1) ((unsigned short*)Cb)[(size_t)row * ldc + colL] = f2bf(v);
                else           ((float*)Cb)[(size_t)row * ldc + colL] = v;
                if (XTRA) { if (col < 32) aux[(size_t)row * 32 + col] = f2bf(v); }
            }
}

// ---------------------------------------------------------------------------
// Combined weight for fused out-proj+final (proven r7: identical absmax):
// ---------------------------------------------------------------------------
__global__ __launch_bounds__(256) void combine_k(
    const float* __restrict__ lin_w, const float* __restrict__ owf,
    const float* __restrict__ owb, unsigned short* __restrict__ Wcomb)
{
    const int dir = blockIdx.z;
    const float* ow = dir ? owb : owf;
    const int lane = threadIdx.x & 63;
    const int wave = threadIdx.x >> 6;
    const int n = blockIdx.y * 4 + wave;          // 0..511
    const int d = blockIdx.x * 256 + lane * 4;    // 0..1023
    float4 acc = {0.f, 0.f, 0.f, 0.f};
    const float* lrow = lin_w + (size_t)n * 1024 + dir * 512;
    for (int j = 0; j < 512; ++j) {
        const float s = lrow[j];
        const float4 v = *(const float4*)&ow[(size_t)j * 1024 + d];
        acc.x = fmaf(s, v.x, acc.x); acc.y = fmaf(s, v.y, acc.y);
        acc.z = fmaf(s, v.z, acc.z); acc.w = fmaf(s, v.w, acc.w);
    }
    ushort4 o;
    o.x = f2bf(acc.x); o.y = f2bf(acc.y); o.z = f2bf(acc.z); o.w = f2bf(acc.w);
    *(ushort4*)&Wcomb[(size_t)n * 2048 + dir * 1024 + d] = o;
}

// ---------------------------------------------------------------------------
// fp32 -> bf16 conversion: 6 weight segments, one launch.
// ---------------------------------------------------------------------------
struct CvtArgs { const float* s[6]; unsigned short* d[6]; int n[6]; };
__global__ __launch_bounds__(256) void cvt_k(CvtArgs a)
{
    const int sid = blockIdx.y;
    const float* s = a.s[sid];
    unsigned short* d = a.d[sid];
    const int n4 = a.n[sid] >> 2;
    for (int i = blockIdx.x * 256 + threadIdx.x; i < n4; i += gridDim.x * 256) {
        const float4 v = ((const float4*)s)[i];
        ushort4 o; o.x = f2bf(v.x); o.y = f2bf(v.y); o.z = f2bf(v.z); o.w = f2bf(v.w);
        ((ushort4*)d)[i] = o;
    }
}
__global__ __launch_bounds__(256) void cvtx_k(const float* __restrict__ s,
                                              unsigned short* __restrict__ d, int n4)
{
    for (int i = blockIdx.x * 256 + threadIdx.x; i < n4; i += gridDim.x * 256) {
        const float4 v = ((const float4*)s)[i];
        ushort4 o; o.x = f2bf(v.x); o.y = f2bf(v.y); o.z = f2bf(v.z); o.w = f2bf(v.w);
        ((ushort4*)d)[i] = o;
    }
}

// A_log -> -exp(A_log)*log2(e) tables for both dirs (used by fix_k)
__global__ __launch_bounds__(256) void alprep_k(const float* __restrict__ af,
                                                const float* __restrict__ ab,
                                                float* __restrict__ of,
                                                float* __restrict__ ob)
{
    const int i = blockIdx.x * 256 + threadIdx.x;
    if (i < 16384) {
        of[i] = -expf(af[i]) * 1.4426950408889634f;
        ob[i] = -expf(ab[i]) * 1.4426950408889634f;
    }
}

// ---------------------------------------------------------------------------
// Causal depthwise conv(4) + bias + SiLU, both dirs; reads xc (ld 1024).
// Round 6: 4 timesteps per block via 7-row sliding window (same tap order,
// bit-exact; 16->7 input row loads per output quad).
// ---------------------------------------------------------------------------
__global__ __launch_bounds__(256) void conv_silu_k(
    const unsigned short* __restrict__ xc_f, const float* __restrict__ cw_f,
    const float* __restrict__ cb_f, unsigned short* __restrict__ xi_f,
    const unsigned short* __restrict__ xc_b, const float* __restrict__ cw_b,
    const float* __restrict__ cb_b, unsigned short* __restrict__ xi_b)
{
    const int dir = blockIdx.y;
    const unsigned short* xc = dir ? xc_b : xc_f;
    const float* cw = dir ? cw_b : cw_f;
    const float* cb = dir ? cb_b : cb_f;
    unsigned short* xi = dir ? xi_b : xi_f;

    const int bt = blockIdx.x;                // Mg/4 blocks
    const int b = bt >> 9;                    // LSEQ/4 = 512 blocks per batch
    const int t0 = (bt & 511) << 2;
    const int d = threadIdx.x << 2;

    float w[4][4];
#pragma unroll
    for (int i = 0; i < 4; ++i) {
        const float4 wr = *(const float4*)&cw[(d + i) * 4];
        w[i][0] = wr.x; w[i][1] = wr.y; w[i][2] = wr.z; w[i][3] = wr.w;
    }
    const float4 bias = *(const float4*)&cb[d];

    float4 r[7];
#pragma unroll
    for (int j = 0; j < 7; ++j) {
        const int row = dir ? (LSEQ + 2 - t0 - j) : (t0 - 3 + j);
        if ((unsigned)row < (unsigned)LSEQ) {
            const ushort4 v = *(const ushort4*)&xc[(size_t)(b * LSEQ + row) * 1024 + d];
            r[j].x = bf2f(v.x); r[j].y = bf2f(v.y); r[j].z = bf2f(v.z); r[j].w = bf2f(v.w);
        } else {
            r[j].x = 0.f; r[j].y = 0.f; r[j].z = 0.f; r[j].w = 0.f;
        }
    }
#pragma unroll
    for (int tt = 0; tt < 4; ++tt) {
        float4 acc = bias;
#pragma unroll
        for (int k = 0; k < 4; ++k) {
            const float4 v = r[tt + k];
            acc.x += w[0][k] * v.x; acc.y += w[1][k] * v.y;
            acc.z += w[2][k] * v.z; acc.w += w[3][k] * v.w;
        }
        ushort4 st;
        st.x = f2bf(silu_f(acc.x)); st.y = f2bf(silu_f(acc.y));
        st.z = f2bf(silu_f(acc.z)); st.w = f2bf(silu_f(acc.w));
        *(ushort4*)&xi[(size_t)(b * LSEQ + t0 + tt) * 1024 + d] = st;
    }
}

// ---------------------------------------------------------------------------
// Selective scan, seq-split P=2 (round 6):
//  - sy ALIASED onto sdtx, scum onto sdt (safe: within an iteration the
//    di-group [one wave] reads sdt/sdtx[di][tt..tt+3] before the lead thread
//    writes the same region; DS ops within a wave are ordered; cross-wave
//    consumers are behind barD; next-chunk overwrite is behind barC-pre).
//    LDS 49.2 KB -> 31.5 KB => 4 blocks/CU resident (grid provides 4/CU).
// ---------------------------------------------------------------------------
__device__ __forceinline__ float row_sum8(float x) {
    x += __int_as_float(__builtin_amdgcn_update_dpp(0, __float_as_int(x), 0xB1, 0xF, 0xF, true));  // quad xor1
    x += __int_as_float(__builtin_amdgcn_update_dpp(0, __float_as_int(x), 0x4E, 0xF, 0xF, true));  // quad xor2
    x += __int_as_float(__builtin_amdgcn_update_dpp(0, __float_as_int(x), 0x141, 0xF, 0xF, true)); // row_half_mirror
    return x;
}

struct ScanPair {
    const unsigned short* dblh[2];   // (rows x 32) bf16
    const unsigned short* dtw[2];    // (1024 x 32) bf16
    const float* dtb[2];             // (1024) f32
    unsigned short* xiy[2];          // (rows x 1024) bf16, in/out
    const float* dbl[2];             // (rows x 64) f32, B/C in cols 32..63
    const unsigned short* zb[2];     // (rows x 1024) bf16, z
    const float* Al[2];
    const float* Dp[2];
    float* cumg[2];                  // (G*1024 x 1024) f32: part-1 cumsum(dt)
    float* he[2];                    // (G*1024 x 16) f32: part-0 h_end
};

__global__ __launch_bounds__(256, 4) void scan_k(ScanPair sp)
{
    __shared__ unsigned short sxi[64][40];       // [t][ch] raw bf16
    __shared__ float sdt[32][68], sdtx[32][68];  // [ch][t]; scum aliases sdt,
                                                 // sy aliases sdtx (see header)
    __shared__ float sB2[8][140], sC2[8][140];   // [np][t*2+half]: {B_np, B_np+8}

    const int dir = blockIdx.z;
    const unsigned short* dblh = sp.dblh[dir];
    const unsigned short* dtw  = sp.dtw[dir];
    const float* dtb           = sp.dtb[dir];
    unsigned short* xiy        = sp.xiy[dir];
    const float* dbl           = sp.dbl[dir];
    const unsigned short* zz   = sp.zb[dir];
    const float* Al            = sp.Al[dir];
    const float* Dpp           = sp.Dp[dir];
    float* cumg                = sp.cumg[dir];
    float* hep                 = sp.he[dir];

    const int by = blockIdx.y;
    const int b = by >> 1, part = by & 1;
    const int rbase = b * LSEQ + part * (LSEQ / 2);
    const int d0 = blockIdx.x << 5;
    const int tid = threadIdx.x;
    const int wave = tid >> 6, lane = tid & 63;
    const int l15 = lane & 15, l4 = lane >> 4;
    const int di = tid >> 3, np = tid & 7;     // inner-loop mapping
    const int lr = tid >> 2, lc = tid & 3;     // stage/epilogue mapping
    const bool lead = (np == 0);

    // A constants pre-scaled by log2(e) so exp2 needs no extra mul
    const f32x2 ALv = {-expf(Al[(d0 + di) * 16 + np]) * 1.4426950408889634f,
                       -expf(Al[(d0 + di) * 16 + np + 8]) * 1.4426950408889634f};

    // dt MFMA B-fragments: rows = the block's 32 channels (two 16-ch halves)
    const short8 dtwf0 = *(const short8*)&dtw[(size_t)(d0 + l15) * 32 + l4 * 8];
    const short8 dtwf1 = *(const short8*)&dtw[(size_t)(d0 + 16 + l15) * 32 + l4 * 8];
    const float dtb0 = dtb[d0 + l15], dtb1 = dtb[d0 + 16 + l15];

    float dpv[8];
#pragma unroll
    for (int i = 0; i < 8; ++i) dpv[i] = Dpp[d0 + lc * 8 + i];

    ushort4 pxi0, pxi1;
    float4 pB, pC;
    short8 pA;
    auto issue_loads = [&](int c) {
        const size_t r = (size_t)rbase + c * 64 + lr;
        pxi0 = *(const ushort4*)&xiy[r * 1024 + d0 + lc * 8];
        pxi1 = *(const ushort4*)&xiy[r * 1024 + d0 + lc * 8 + 4];
        pB   = *(const float4*)&dbl[r * 64 + 32 + lc * 4];
        pC   = *(const float4*)&dbl[r * 64 + 48 + lc * 4];
        // dt MFMA A-fragment: rows = this wave's 16 timesteps of the chunk
        pA   = *(const short8*)&dblh[(size_t)(rbase + c * 64 + wave * 16 + l15) * 32 + l4 * 8];
    };
    issue_loads(0);

    constexpr int NT = (LSEQ / 2) / 64;   // 16 chunks per partition
    f32x2 h = {0.f, 0.f};
    float cum = 0.0f;
    for (int c = 0; c < NT; ++c) {
        const int t0 = c * 64;
        // ---- stage xi raw bf16 [t][ch] and B/C pairs ----
        *(ushort4*)&sxi[lr][lc * 8]     = pxi0;
        *(ushort4*)&sxi[lr][lc * 8 + 4] = pxi1;
        {
            const float bv[4] = {pB.x, pB.y, pB.z, pB.w};
            const float cv[4] = {pC.x, pC.y, pC.z, pC.w};
#pragma unroll
            for (int i = 0; i < 4; ++i) {
                const int n = lc * 4 + i;
                sB2[n & 7][lr * 2 + (n >> 3)] = bv[i];
                sC2[n & 7][lr * 2 + (n >> 3)] = cv[i];
            }
        }
        __syncthreads();   // barC-pre: stage visible to all
        // ---- dt phase: MFMA -> softplus -> sdt, and dtx = dt*xi -> sdtx ----
        {
            f32x4 z4 = {0.f, 0.f, 0.f, 0.f};
            f32x4 dacc0 = __builtin_amdgcn_mfma_f32_16x16x32_bf16(pA, dtwf0, z4, 0, 0, 0);
            f32x4 dacc1 = __builtin_amdgcn_mfma_f32_16x16x32_bf16(pA, dtwf1, z4, 0, 0, 0);
            const int tq = wave * 16 + l4 * 4;
            float4 xi0, xi1;
            xi0.x = bf2f(sxi[tq + 0][l15]);      xi0.y = bf2f(sxi[tq + 1][l15]);
            xi0.z = bf2f(sxi[tq + 2][l15]);      xi0.w = bf2f(sxi[tq + 3][l15]);
            xi1.x = bf2f(sxi[tq + 0][16 + l15]); xi1.y = bf2f(sxi[tq + 1][16 + l15]);
            xi1.z = bf2f(sxi[tq + 2][16 + l15]); xi1.w = bf2f(sxi[tq + 3][16 + l15]);
            float4 dv0, dv1, dx0, dx1;
            dv0.x = softplus_f(dacc0[0] + dtb0); dv0.y = softplus_f(dacc0[1] + dtb0);
            dv0.z = softplus_f(dacc0[2] + dtb0); dv0.w = softplus_f(dacc0[3] + dtb0);
            dv1.x = softplus_f(dacc1[0] + dtb1); dv1.y = softplus_f(dacc1[1] + dtb1);
            dv1.z = softplus_f(dacc1[2] + dtb1); dv1.w = softplus_f(dacc1[3] + dtb1);
            dx0.x = dv0.x * xi0.x; dx0.y = dv0.y * xi0.y;
            dx0.z = dv0.z * xi0.z; dx0.w = dv0.w * xi0.w;
            dx1.x = dv1.x * xi1.x; dx1.y = dv1.y * xi1.y;
            dx1.z = dv1.z * xi1.z; dx1.w = dv1.w * xi1.w;
            *(float4*)&sdt[l15][tq]       = dv0;
            *(float4*)&sdt[16 + l15][tq]  = dv1;
            *(float4*)&sdtx[l15][tq]      = dx0;
            *(float4*)&sdtx[16 + l15][tq] = dx1;
        }
        const ushort4 oxi0 = pxi0, oxi1 = pxi1;
        ushort4 pz0 = {}, pz1 = {};
        if (part == 0) {
            const int tg = t0 + lr;
            const int tz = dir ? (LSEQ - 1 - tg) : tg;
            pz0 = *(const ushort4*)&zz[((size_t)b * LSEQ + tz) * 1024 + d0 + lc * 8];
            pz1 = *(const ushort4*)&zz[((size_t)b * LSEQ + tz) * 1024 + d0 + lc * 8 + 4];
        }
        if (c + 1 < NT) issue_loads(c + 1);
        __syncthreads();   // barC: sdt/sdtx visible, inner may start
        // ---- inner scan: 64 timesteps, 2 states per thread (f32x2 packed);
        //      sy->sdtx, scum->sdt in-place (read-before-write within wave) ----
#pragma unroll 4
        for (int tt = 0; tt < 64; tt += 4) {
            const float4 d4 = *(const float4*)&sdt[di][tt];
            const float4 u4 = *(const float4*)&sdtx[di][tt];
            const float4 bA = *(const float4*)&sB2[np][tt * 2];
            const float4 bB = *(const float4*)&sB2[np][tt * 2 + 4];
            const float4 cA = *(const float4*)&sC2[np][tt * 2];
            const float4 cB = *(const float4*)&sC2[np][tt * 2 + 4];
            float4 ppv;
            {
                f32x2 e = ALv * d4.x;
                e.x = EXP2F(e.x); e.y = EXP2F(e.y);
                const f32x2 b2 = {bA.x, bA.y};
                const f32x2 c2 = {cA.x, cA.y};
                h = e * h + b2 * u4.x;
                const f32x2 pc = h * c2;
                ppv.x = row_sum8(pc.x + pc.y);
            }
            {
                f32x2 e = ALv * d4.y;
                e.x = EXP2F(e.x); e.y = EXP2F(e.y);
                const f32x2 b2 = {bA.z, bA.w};
                const f32x2 c2 = {cA.z, cA.w};
                h = e * h + b2 * u4.y;
                const f32x2 pc = h * c2;
                ppv.y = row_sum8(pc.x + pc.y);
            }
            {
                f32x2 e = ALv * d4.z;
                e.x = EXP2F(e.x); e.y = EXP2F(e.y);
                const f32x2 b2 = {bB.x, bB.y};
                const f32x2 c2 = {cB.x, cB.y};
                h = e * h + b2 * u4.z;
                const f32x2 pc = h * c2;
                ppv.z = row_sum8(pc.x + pc.y);
            }
            {
                f32x2 e = ALv * d4.w;
                e.x = EXP2F(e.x); e.y = EXP2F(e.y);
                const f32x2 b2 = {bB.z, bB.w};
                const f32x2 c2 = {cB.z, cB.w};
                h = e * h + b2 * u4.w;
                const f32x2 pc = h * c2;
                ppv.w = row_sum8(pc.x + pc.y);
            }
            if (part) {
                const float c0 = cum + d4.x, c1 = c0 + d4.y;
                const float c2s = c1 + d4.z, c3 = c2s + d4.w;
                cum = c3;
                if (lead) {
                    float4 cc; cc.x = c0; cc.y = c1; cc.z = c2s; cc.w = c3;
                    *(float4*)&sdt[di][tt] = cc;    // scum alias
                }
            }
            if (lead) *(float4*)&sdtx[di][tt] = ppv; // sy alias
        }
        __syncthreads();   // barD: sy/scum complete; staging arrays free
        // ---- epilogue ----
        if (part == 0) {
            const size_t r = (size_t)rbase + t0 + lr;
            ushort4 s0, s1;
            s0.x = f2bf(fmaf(bf2f(oxi0.x), dpv[0], sdtx[lc * 8 + 0][lr]) * silu_f(bf2f(pz0.x)));
            s0.y = f2bf(fmaf(bf2f(oxi0.y), dpv[1], sdtx[lc * 8 + 1][lr]) * silu_f(bf2f(pz0.y)));
            s0.z = f2bf(fmaf(bf2f(oxi0.z), dpv[2], sdtx[lc * 8 + 2][lr]) * silu_f(bf2f(pz0.z)));
            s0.w = f2bf(fmaf(bf2f(oxi0.w), dpv[3], sdtx[lc * 8 + 3][lr]) * silu_f(bf2f(pz0.w)));
            s1.x = f2bf(fmaf(bf2f(oxi1.x), dpv[4], sdtx[lc * 8 + 4][lr]) * silu_f(bf2f(pz1.x)));
            s1.y = f2bf(fmaf(bf2f(oxi1.y), dpv[5], sdtx[lc * 8 + 5][lr]) * silu_f(bf2f(pz1.y)));
            s1.z = f2bf(fmaf(bf2f(oxi1.z), dpv[6], sdtx[lc * 8 + 6][lr]) * silu_f(bf2f(pz1.z)));
            s1.w = f2bf(fmaf(bf2f(oxi1.w), dpv[7], sdtx[lc * 8 + 7][lr]) * silu_f(bf2f(pz1.w)));
            *(ushort4*)&xiy[r * 1024 + d0 + lc * 8] = s0;
            *(ushort4*)&xiy[r * 1024 + d0 + lc * 8 + 4] = s1;
        } else {
            // raw y + xi*Dp as bf16 in place; cum coalesced f32
            const size_t r = (size_t)rbase + t0 + lr;
            ushort4 s0, s1;
            s0.x = f2bf(fmaf(bf2f(oxi0.x), dpv[0], sdtx[lc * 8 + 0][lr]));
            s0.y = f2bf(fmaf(bf2f(oxi0.y), dpv[1], sdtx[lc * 8 + 1][lr]));
            s0.z = f2bf(fmaf(bf2f(oxi0.z), dpv[2], sdtx[lc * 8 + 2][lr]));
            s0.w = f2bf(fmaf(bf2f(oxi0.w), dpv[3], sdtx[lc * 8 + 3][lr]));
            s1.x = f2bf(fmaf(bf2f(oxi1.x), dpv[4], sdtx[lc * 8 + 4][lr]));
            s1.y = f2bf(fmaf(bf2f(oxi1.y), dpv[5], sdtx[lc * 8 + 5][lr]));
            s1.z = f2bf(fmaf(bf2f(oxi1.z), dpv[6], sdtx[lc * 8 + 6][lr]));
            s1.w = f2bf(fmaf(bf2f(oxi1.w), dpv[7], sdtx[lc * 8 + 7][lr]));
            *(ushort4*)&xiy[r * 1024 + d0 + lc * 8] = s0;
            *(ushort4*)&xiy[r * 1024 + d0 + lc * 8 + 4] = s1;
            float4 c0v, c1v;
            c0v.x = sdt[lc * 8 + 0][lr]; c0v.y = sdt[lc * 8 + 1][lr];
            c0v.z = sdt[lc * 8 + 2][lr]; c0v.w = sdt[lc * 8 + 3][lr];
            c1v.x = sdt[lc * 8 + 4][lr]; c1v.y = sdt[lc * 8 + 5][lr];
            c1v.z = sdt[lc * 8 + 6][lr]; c1v.w = sdt[lc * 8 + 7][lr];
            const size_t pr = (size_t)(b * (LSEQ / 2) + t0 + lr) * 1024 + d0 + lc * 8;
            *(float4*)&cumg[pr]     = c0v;
            *(float4*)&cumg[pr + 4] = c1v;
        }
    }
    if (part == 0) {
        float* hh = &hep[((size_t)b * 1024 + d0 + di) * 16 + np];
        hh[0] = h.x; hh[8] = h.y;
    }
}

// ---------------------------------------------------------------------------
// Part-1 fixup: block = 32 ch x 256 t-quarter x batch; AL/HE/C staged ONCE
// in LDS, loop over 32 iterations of 8 t. In-place on xiy.
// ---------------------------------------------------------------------------
struct FixArgs {
    const float* cumg[2]; const float* he[2]; const float* al2[2];
    const float* dbl[2];  const unsigned short* zb[2]; unsigned short* xiy[2];
};
__global__ __launch_bounds__(256) void fix_k(FixArgs a)
{
    const int dir = blockIdx.z;
    const float* cumg          = a.cumg[dir];
    const float* he            = a.he[dir];
    const float* al2           = a.al2[dir];
    const float* dbl           = a.dbl[dir];
    const unsigned short* zz   = a.zb[dir];
    unsigned short* xiy        = a.xiy[dir];

    __shared__ float sAL[32][17], sHE[32][17];
    __shared__ float sCt[256][16];

    const int tid = threadIdx.x;
    const int d0 = blockIdx.x << 5;           // 32-ch block
    const int by = blockIdx.y;
    const int b = by >> 2, q = by & 3;        // quarter (256 t) of part 1
    const int tq0 = q << 8;

    for (int i = tid; i < 512; i += 256) {
        const int dd = i >> 4, nn = i & 15;
        sAL[dd][nn] = al2[(size_t)(d0 + dd) * 16 + nn];
        sHE[dd][nn] = he[((size_t)b * 1024 + d0 + dd) * 16 + nn];
    }
    for (int i = tid; i < 4096; i += 256) {
        const int tt = i >> 4, nn = i & 15;
        sCt[tt][nn] = dbl[((size_t)b * LSEQ + (LSEQ / 2) + tq0 + tt) * 64 + 48 + nn];
    }
    __syncthreads();

    const int ts = tid >> 5, dd = tid & 31;
    for (int it = 0; it < 32; ++it) {
        const int tl = tq0 + it * 8 + ts;                 // part-local t
        const int tglob = (LSEQ / 2) + tl;
        const size_t grow = (size_t)b * LSEQ + tglob;
        const float cv = cumg[((size_t)b * (LSEQ / 2) + tl) * 1024 + d0 + dd];
        const float yv0 = bf2f(xiy[grow * 1024 + d0 + dd]);
        const int tz = dir ? (LSEQ - 1 - tglob) : tglob;
        const float z = bf2f(zz[((size_t)b * LSEQ + tz) * 1024 + d0 + dd]);
        float corr = 0.f;
#pragma unroll
        for (int n = 0; n < 16; ++n)
            corr = fmaf(sCt[it * 8 + ts][n] * sHE[dd][n], EXP2F(sAL[dd][n] * cv), corr);
        xiy[grow * 1024 + d0 + dd] = f2bf((yv0 + corr) * silu_f(z));
    }
}

// ---------------------------------------------------------------------------
extern "C" void kernel_launch(void* const* d_in, const int* in_sizes, int n_in,
                              void* d_out, int out_size, void* d_ws, size_t ws_size,
                              hipStream_t stream)
{
    const float* x      = (const float*)d_in[0];
    const float* f_in_w = (const float*)d_in[1];
    const float* f_cw   = (const float*)d_in[2];
    const float* f_cb   = (const float*)d_in[3];
    const float* f_xp   = (const float*)d_in[4];
    const float* f_dtw  = (const float*)d_in[5];
    const float* f_dtb  = (const float*)d_in[6];
    const float* f_Al   = (const float*)d_in[7];
    const float* f_Dp   = (const float*)d_in[8];
    const float* f_ow   = (const float*)d_in[9];
    const float* b_in_w = (const float*)d_in[10];
    const float* b_cw   = (const float*)d_in[11];
    const float* b_cb   = (const float*)d_in[12];
    const float* b_xp   = (const float*)d_in[13];
    const float* b_dtw  = (const float*)d_in[14];
    const float* b_dtb  = (const float*)d_in[15];
    const float* b_Al   = (const float*)d_in[16];
    const float* b_Dp   = (const float*)d_in[17];
    const float* b_ow   = (const float*)d_in[18];
    const float* lin_w  = (const float*)d_in[19];
    const float* lin_b  = (const float*)d_in[20];
    float* out = (float*)d_out;

    char* p = (char*)d_ws;
    auto take = [&](size_t bytes) -> char* {
        char* r = p; p += (bytes + 255) & ~(size_t)255; return r;
    };

    // persistent bf16 weights + AL2 tables
    unsigned short* wif  = (unsigned short*)take((size_t)2048 * 512 * 2);
    unsigned short* wib  = (unsigned short*)take((size_t)2048 * 512 * 2);
    unsigned short* wxf  = (unsigned short*)take((size_t)64 * 1024 * 2);
    unsigned short* wxb  = (unsigned short*)take((size_t)64 * 1024 * 2);
    unsigned short* wdtf = (unsigned short*)take((size_t)1024 * 32 * 2);
    unsigned short* wdtb = (unsigned short*)take((size_t)1024 * 32 * 2);
    unsigned short* wcmb = (unsigned short*)take((size_t)512 * 2048 * 2);
    float* al2f = (float*)take((size_t)1024 * 16 * 4);
    float* al2b = (float*)take((size_t)1024 * 16 * 4);

    const size_t used = (size_t)(p - (char*)d_ws);
    // per-row bytes: xbf 1024 + per dir (xc 2048 + zb 2048 + xiy 2048 + dbl 256
    //                                    + dblh 64); cum ALIASED onto xc.
    const size_t perRow = 1024 + 2 * (2048 + 2048 + 2048 + 256 + 64);
    int G = 1;
    for (int g = 8; g >= 1; g >>= 1) {
        const size_t need = used + (size_t)g * LSEQ * perRow + (size_t)g * 2 * 1024 * 16 * 4 + 16384;
        if (need <= ws_size || g == 1) { G = g; break; }
    }

    CvtArgs ca;
    ca.s[0] = f_in_w; ca.d[0] = wif;  ca.n[0] = 2048 * 512;
    ca.s[1] = b_in_w; ca.d[1] = wib;  ca.n[1] = 2048 * 512;
    ca.s[2] = f_xp;   ca.d[2] = wxf;  ca.n[2] = 64 * 1024;
    ca.s[3] = b_xp;   ca.d[3] = wxb;  ca.n[3] = 64 * 1024;
    ca.s[4] = f_dtw;  ca.d[4] = wdtf; ca.n[4] = 1024 * 32;
    ca.s[5] = b_dtw;  ca.d[5] = wdtb; ca.n[5] = 1024 * 32;
    cvt_k<<<dim3(128, 6), 256, 0, stream>>>(ca);

    alprep_k<<<dim3(64), 256, 0, stream>>>(f_Al, b_Al, al2f, al2b);

    // combined (lin_w @ out_w) weight, bf16, (512 x 2048) — proven r7
    combine_k<<<dim3(4, 128, 2), 256, 0, stream>>>(lin_w, f_ow, b_ow, wcmb);

    char* pg0 = p;
    for (int g0 = 0; g0 < NBATCH; g0 += G) {
        const int Mg = G * LSEQ;
        p = pg0;
        unsigned short* xbf   = (unsigned short*)take((size_t)Mg * 512 * 2);
        unsigned short* xc_f  = (unsigned short*)take((size_t)Mg * 1024 * 2);
        unsigned short* zb_f  = (unsigned short*)take((size_t)Mg * 1024 * 2);
        unsigned short* xc_b  = (unsigned short*)take((size_t)Mg * 1024 * 2);
        unsigned short* zb_b  = (unsigned short*)take((size_t)Mg * 1024 * 2);
        unsigned short* xiy_f = (unsigned short*)take((size_t)Mg * 1024 * 2);
        unsigned short* xiy_b = (unsigned short*)take((size_t)Mg * 1024 * 2);
        float* dbl_f          = (float*)take((size_t)Mg * 64 * 4);
        float* dbl_b          = (float*)take((size_t)Mg * 64 * 4);
        unsigned short* dblh_f= (unsigned short*)take((size_t)Mg * 32 * 2);
        unsigned short* dblh_b= (unsigned short*)take((size_t)Mg * 32 * 2);
        float* he_f           = (float*)take((size_t)G * 1024 * 16 * 4);
        float* he_b           = (float*)take((size_t)G * 1024 * 16 * 4);
        // cum aliased onto dead conv-input buffers (exact size match)
        float* cum_f = (float*)xc_f;
        float* cum_b = (float*)xc_b;

        const float* xg = x + (size_t)g0 * LSEQ * 512;
        float* outg = out + (size_t)g0 * LSEQ * 512;

        cvtx_k<<<dim3(512), 256, 0, stream>>>(xg, xbf, Mg * 512 / 4);

        GemmPair g1 = {};   // in-proj: split output xc (cols<1024) / zb (>=1024)
        g1.A[0] = xbf; g1.A[1] = xbf; g1.W[0] = wif; g1.W[1] = wib;
        g1.C[0] = xc_f; g1.C[1] = xc_b; g1.Cz[0] = zb_f; g1.Cz[1] = zb_b;
        gemm_mfma<2,2,1,0,0,1><<<dim3(Mg/128, 16, 2), 256, 0, stream>>>(g1, 512, 512, 1024, 512);

        conv_silu_k<<<dim3(Mg/4, 2), 256, 0, stream>>>(xc_f, f_cw, f_cb, xiy_f,
                                                       xc_b, b_cw, b_cb, xiy_b);

        GemmPair g2 = {};   // x-proj: dbl f32 (ldc 64) + bf16 cols<32 (dblh)
        g2.A[0] = xiy_f; g2.A[1] = xiy_b; g2.W[0] = wxf; g2.W[1] = wxb;
        g2.C[0] = dbl_f; g2.C[1] = dbl_b; g2.aux[0] = dblh_f; g2.aux[1] = dblh_b;
        gemm_mfma<2,1,0,0,1><<<dim3(Mg/128, 1, 2), 128, 0, stream>>>(g2, 1024, 1024, 64, 1024);

        ScanPair spp = {};  // scan: seq-split P=2, 1024 rows per block
        spp.dblh[0] = dblh_f; spp.dblh[1] = dblh_b;
        spp.dtw[0] = wdtf;    spp.dtw[1] = wdtb;
        spp.dtb[0] = f_dtb;   spp.dtb[1] = b_dtb;
        spp.xiy[0] = xiy_f;   spp.xiy[1] = xiy_b;
        spp.dbl[0] = dbl_f;   spp.dbl[1] = dbl_b;
        spp.zb[0] = zb_f;     spp.zb[1] = zb_b;
        spp.Al[0] = f_Al;     spp.Al[1] = b_Al;
        spp.Dp[0] = f_Dp;     spp.Dp[1] = b_Dp;
        spp.cumg[0] = cum_f;  spp.cumg[1] = cum_b;
        spp.he[0] = he_f;     spp.he[1] = he_b;
        scan_k<<<dim3(32, G * 2, 2), 256, 0, stream>>>(spp);

        FixArgs fa = {};
        fa.cumg[0] = cum_f; fa.cumg[1] = cum_b;
        fa.he[0] = he_f;    fa.he[1] = he_b;
        fa.al2[0] = al2f;   fa.al2[1] = al2b;
        fa.dbl[0] = dbl_f;  fa.dbl[1] = dbl_b;
        fa.zb[0] = zb_f;    fa.zb[1] = zb_b;
        fa.xiy[0] = xiy_f;  fa.xiy[1] = xiy_b;
        fix_k<<<dim3(32, G * 4, 2), 256, 0, stream>>>(fa);

        // fused out-proj+final: out = [y_f | rev(y_b)] @ Wcomb^T + lin_b (K=2048)
        GemmPair g5 = {};
        g5.A[0] = xiy_f; g5.A2[0] = xiy_b; g5.W[0] = wcmb;
        g5.bias[0] = lin_b; g5.C[0] = outg;
        gemm_mfma<2,2,0,1024,0><<<dim3(Mg/128, 4, 1), 256, 0, stream>>>(g5, 1024, 2048, 512, 2048);
    }
}

// Round 7
// 661.670 us; speedup vs baseline: 1.4233x; 1.0311x over previous
//
#include <hip/hip_runtime.h>
#include <cmath>

#define LSEQ 2048
#define NBATCH 8

typedef __attribute__((ext_vector_type(8))) short short8;
typedef __attribute__((ext_vector_type(4))) float f32x4;
typedef __attribute__((ext_vector_type(2))) float f32x2;

__device__ __forceinline__ float silu_f(float x) {
    return x * __builtin_amdgcn_rcpf(1.0f + __expf(-x));
}
__device__ __forceinline__ float softplus_f(float x) {
    return fmaxf(x, 0.0f) + __logf(1.0f + __expf(-fabsf(x)));
}
__device__ __forceinline__ unsigned short f2bf(float f) {   // RNE fp32->bf16
    unsigned int u = __float_as_uint(f);
    u += 0x7FFFu + ((u >> 16) & 1u);
    return (unsigned short)(u >> 16);
}
__device__ __forceinline__ float bf2f(unsigned short h) {
    return __uint_as_float(((unsigned int)h) << 16);
}
__device__ __forceinline__ void gload_lds16(const void* g, void* l) {
    __builtin_amdgcn_global_load_lds((const __attribute__((address_space(1))) void*)g,
                                     (__attribute__((address_space(3))) void*)l, 16, 0, 0);
}

#if defined(__has_builtin)
#if __has_builtin(__builtin_amdgcn_exp2f)
#define EXP2F(x) __builtin_amdgcn_exp2f(x)
#endif
#endif
#ifndef EXP2F
#define EXP2F(x) __expf((x) * 0.69314718055994531f)
#endif

// fwd/bwd operand pairs; blockIdx.z selects direction
struct GemmPair {
    const unsigned short* A[2];
    const unsigned short* A2[2];   // DUAL second A (second K-half, row-reversed)
    const unsigned short* W[2];
    const float* bias[2];
    void* C[2];
    void* Cz[2];                   // SPLIT: cols >=1024 go here (ld = ldc)
    unsigned short* aux[2];
};

// ---------------------------------------------------------------------------
// bf16 MFMA GEMM (NT), r4-proven config: BK=32, scalar epilogue.
// SPLIT: N=2048 output split into two ld-1024 buffers (C: cols<1024, Cz: >=1024)
// ---------------------------------------------------------------------------
template<int WGM, int WGN, int OMODE, int DK, int XTRA, int SPLIT = 0>
__global__ __launch_bounds__(WGM* WGN * 64) void gemm_mfma(GemmPair gp, int lda, int ldw,
                                                           int ldc, int K)
{
    constexpr int NW = WGM * WGN;
    constexpr int TM = WGM * 64, TN = WGN * 64;
    __shared__ unsigned short As[TM * 32];
    __shared__ unsigned short Bs[TN * 32];
    const int dir = blockIdx.z;
    const unsigned short* A  = gp.A[dir];
    const unsigned short* A2 = gp.A2[dir];
    const unsigned short* W  = gp.W[dir];
    const float* bias        = gp.bias[dir];
    void* Cout               = gp.C[dir];
    void* Czout              = gp.Cz[dir];
    unsigned short* aux      = gp.aux[dir];

    const int tid = threadIdx.x;
    const int wave = tid >> 6, lane = tid & 63;
    const int wm = wave / WGN, wn = wave % WGN;
    const int m0 = blockIdx.x * TM, n0 = blockIdx.y * TN;
    const int l15 = lane & 15, l4 = lane >> 4;
    const int srow = lane >> 2, schunk = (lane & 3) * 8;

    f32x4 acc[4][4] = {};

    for (int k0 = 0; k0 < K; k0 += 32) {
        __syncthreads();
        for (int s = wave; s < TM / 16; s += NW) {
            const int gr = m0 + s * 16 + srow;
            const unsigned short* g;
            if (DK != 0 && k0 >= DK)
                g = A2 + (size_t)(gr ^ (LSEQ - 1)) * lda + (k0 - DK) + schunk;
            else
                g = A + (size_t)gr * lda + k0 + schunk;
            gload_lds16(g, (char*)As + (size_t)s * 1024);
        }
        for (int s = wave; s < TN / 16; s += NW) {
            const int gr = n0 + s * 16 + srow;
            const unsigned short* g = W + (size_t)gr * ldw + k0 + schunk;
            gload_lds16(g, (char*)Bs + (size_t)s * 1024);
        }
        __syncthreads();
        short8 af[4], bfr[4];
#pragma unroll
        for (int mi = 0; mi < 4; ++mi)
            af[mi] = *(const short8*)&As[(wm * 64 + mi * 16 + l15) * 32 + l4 * 8];
#pragma unroll
        for (int ni = 0; ni < 4; ++ni)
            bfr[ni] = *(const short8*)&Bs[(wn * 64 + ni * 16 + l15) * 32 + l4 * 8];
#pragma unroll
        for (int mi = 0; mi < 4; ++mi)
#pragma unroll
            for (int ni = 0; ni < 4; ++ni)
                acc[mi][ni] = __builtin_amdgcn_mfma_f32_16x16x32_bf16(af[mi], bfr[ni], acc[mi][ni], 0, 0, 0);
    }

    void* Cb = (SPLIT && blockIdx.y * TN >= 1024) ? Czout : Cout;
#pragma unroll
    for (int mi = 0; mi < 4; ++mi)
#pragma unroll
        for (int ni = 0; ni < 4; ++ni)
#pragma unroll
            for (int r = 0; r < 4; ++r) {
                const int row = m0 + wm * 64 + mi * 16 + l4 * 4 + r;
                const int col = n0 + wn * 64 + ni * 16 + l15;
                const int colL = SPLIT ? (col & 1023) : col;
                float v = acc[mi][ni][r];
                if (bias) v += bias[col];
                if (OMODE & 1) ((unsigned short*)Cb)[(size_t)row * ldc + colL] = f2bf(v);
                else           ((float*)Cb)[(size_t)row * ldc + colL] = v;
                if (XTRA) { if (col < 32) aux[(size_t)row * 32 + col] = f2bf(v); }
            }
}

// ---------------------------------------------------------------------------
// Combined weight for fused out-proj+final (proven r7: identical absmax):
// ---------------------------------------------------------------------------
__global__ __launch_bounds__(256) void combine_k(
    const float* __restrict__ lin_w, const float* __restrict__ owf,
    const float* __restrict__ owb, unsigned short* __restrict__ Wcomb)
{
    const int dir = blockIdx.z;
    const float* ow = dir ? owb : owf;
    const int lane = threadIdx.x & 63;
    const int wave = threadIdx.x >> 6;
    const int n = blockIdx.y * 4 + wave;          // 0..511
    const int d = blockIdx.x * 256 + lane * 4;    // 0..1023
    float4 acc = {0.f, 0.f, 0.f, 0.f};
    const float* lrow = lin_w + (size_t)n * 1024 + dir * 512;
    for (int j = 0; j < 512; ++j) {
        const float s = lrow[j];
        const float4 v = *(const float4*)&ow[(size_t)j * 1024 + d];
        acc.x = fmaf(s, v.x, acc.x); acc.y = fmaf(s, v.y, acc.y);
        acc.z = fmaf(s, v.z, acc.z); acc.w = fmaf(s, v.w, acc.w);
    }
    ushort4 o;
    o.x = f2bf(acc.x); o.y = f2bf(acc.y); o.z = f2bf(acc.z); o.w = f2bf(acc.w);
    *(ushort4*)&Wcomb[(size_t)n * 2048 + dir * 1024 + d] = o;
}

// ---------------------------------------------------------------------------
// fp32 -> bf16 conversion: 6 weight segments, one launch.
// ---------------------------------------------------------------------------
struct CvtArgs { const float* s[6]; unsigned short* d[6]; int n[6]; };
__global__ __launch_bounds__(256) void cvt_k(CvtArgs a)
{
    const int sid = blockIdx.y;
    const float* s = a.s[sid];
    unsigned short* d = a.d[sid];
    const int n4 = a.n[sid] >> 2;
    for (int i = blockIdx.x * 256 + threadIdx.x; i < n4; i += gridDim.x * 256) {
        const float4 v = ((const float4*)s)[i];
        ushort4 o; o.x = f2bf(v.x); o.y = f2bf(v.y); o.z = f2bf(v.z); o.w = f2bf(v.w);
        ((ushort4*)d)[i] = o;
    }
}
__global__ __launch_bounds__(256) void cvtx_k(const float* __restrict__ s,
                                              unsigned short* __restrict__ d, int n4)
{
    for (int i = blockIdx.x * 256 + threadIdx.x; i < n4; i += gridDim.x * 256) {
        const float4 v = ((const float4*)s)[i];
        ushort4 o; o.x = f2bf(v.x); o.y = f2bf(v.y); o.z = f2bf(v.z); o.w = f2bf(v.w);
        ((ushort4*)d)[i] = o;
    }
}

// A_log -> -exp(A_log)*log2(e) tables for both dirs (used by fix_k)
__global__ __launch_bounds__(256) void alprep_k(const float* __restrict__ af,
                                                const float* __restrict__ ab,
                                                float* __restrict__ of,
                                                float* __restrict__ ob)
{
    const int i = blockIdx.x * 256 + threadIdx.x;
    if (i < 16384) {
        of[i] = -expf(af[i]) * 1.4426950408889634f;
        ob[i] = -expf(ab[i]) * 1.4426950408889634f;
    }
}

// ---------------------------------------------------------------------------
// Causal depthwise conv(4) + bias + SiLU, both dirs; reads xc (ld 1024).
// Round 7: 8 timesteps per block via 11-row sliding window (same tap order,
// bit-exact; 1.375x input reads vs 1.75x, half the blocks).
// ---------------------------------------------------------------------------
__global__ __launch_bounds__(256) void conv_silu_k(
    const unsigned short* __restrict__ xc_f, const float* __restrict__ cw_f,
    const float* __restrict__ cb_f, unsigned short* __restrict__ xi_f,
    const unsigned short* __restrict__ xc_b, const float* __restrict__ cw_b,
    const float* __restrict__ cb_b, unsigned short* __restrict__ xi_b)
{
    const int dir = blockIdx.y;
    const unsigned short* xc = dir ? xc_b : xc_f;
    const float* cw = dir ? cw_b : cw_f;
    const float* cb = dir ? cb_b : cb_f;
    unsigned short* xi = dir ? xi_b : xi_f;

    const int bt = blockIdx.x;                // Mg/8 blocks
    const int b = bt >> 8;                    // LSEQ/8 = 256 blocks per batch
    const int t0 = (bt & 255) << 3;
    const int d = threadIdx.x << 2;

    float w[4][4];
#pragma unroll
    for (int i = 0; i < 4; ++i) {
        const float4 wr = *(const float4*)&cw[(d + i) * 4];
        w[i][0] = wr.x; w[i][1] = wr.y; w[i][2] = wr.z; w[i][3] = wr.w;
    }
    const float4 bias = *(const float4*)&cb[d];

    float4 r[11];
#pragma unroll
    for (int j = 0; j < 11; ++j) {
        const int row = dir ? (LSEQ + 2 - t0 - j) : (t0 - 3 + j);
        if ((unsigned)row < (unsigned)LSEQ) {
            const ushort4 v = *(const ushort4*)&xc[(size_t)(b * LSEQ + row) * 1024 + d];
            r[j].x = bf2f(v.x); r[j].y = bf2f(v.y); r[j].z = bf2f(v.z); r[j].w = bf2f(v.w);
        } else {
            r[j].x = 0.f; r[j].y = 0.f; r[j].z = 0.f; r[j].w = 0.f;
        }
    }
#pragma unroll
    for (int tt = 0; tt < 8; ++tt) {
        float4 acc = bias;
#pragma unroll
        for (int k = 0; k < 4; ++k) {
            const float4 v = r[tt + k];
            acc.x += w[0][k] * v.x; acc.y += w[1][k] * v.y;
            acc.z += w[2][k] * v.z; acc.w += w[3][k] * v.w;
        }
        ushort4 st;
        st.x = f2bf(silu_f(acc.x)); st.y = f2bf(silu_f(acc.y));
        st.z = f2bf(silu_f(acc.z)); st.w = f2bf(silu_f(acc.w));
        *(ushort4*)&xi[(size_t)(b * LSEQ + t0 + tt) * 1024 + d] = st;
    }
}

// ---------------------------------------------------------------------------
// Selective scan, seq-split P=2 (round 7):
//  - sy in dedicated [32][66] (stride 66 = 2 mod 32 -> epilogue reads 2-way
//    = free; was 4-way via the sdtx alias). scum keeps the sdt alias.
//  - barC-pre removed for part 0 (dt-phase sxi reads are intra-wave: wave w
//    reads rows 16w..16w+15, written by tids 64w..64w+63 = wave w; per-wave
//    DS ops are in-order). Part 1 keeps it: its epilogue reads the cum alias
//    on sdt, which dt(c+1) overwrites.
//    LDS 39936 B -> still exactly 4 blocks/CU.
// ---------------------------------------------------------------------------
__device__ __forceinline__ float row_sum8(float x) {
    x += __int_as_float(__builtin_amdgcn_update_dpp(0, __float_as_int(x), 0xB1, 0xF, 0xF, true));  // quad xor1
    x += __int_as_float(__builtin_amdgcn_update_dpp(0, __float_as_int(x), 0x4E, 0xF, 0xF, true));  // quad xor2
    x += __int_as_float(__builtin_amdgcn_update_dpp(0, __float_as_int(x), 0x141, 0xF, 0xF, true)); // row_half_mirror
    return x;
}

struct ScanPair {
    const unsigned short* dblh[2];   // (rows x 32) bf16
    const unsigned short* dtw[2];    // (1024 x 32) bf16
    const float* dtb[2];             // (1024) f32
    unsigned short* xiy[2];          // (rows x 1024) bf16, in/out
    const float* dbl[2];             // (rows x 64) f32, B/C in cols 32..63
    const unsigned short* zb[2];     // (rows x 1024) bf16, z
    const float* Al[2];
    const float* Dp[2];
    float* cumg[2];                  // (G*1024 x 1024) f32: part-1 cumsum(dt)
    float* he[2];                    // (G*1024 x 16) f32: part-0 h_end
};

__global__ __launch_bounds__(256, 4) void scan_k(ScanPair sp)
{
    __shared__ unsigned short sxi[64][40];       // [t][ch] raw bf16
    __shared__ float sdt[32][68], sdtx[32][68];  // [ch][t]; scum aliases sdt
    __shared__ float sB2[8][140], sC2[8][140];   // [np][t*2+half]: {B_np, B_np+8}
    __shared__ float sy[32][66];                 // [ch][t] (stride 66: 2-way reads)

    const int dir = blockIdx.z;
    const unsigned short* dblh = sp.dblh[dir];
    const unsigned short* dtw  = sp.dtw[dir];
    const float* dtb           = sp.dtb[dir];
    unsigned short* xiy        = sp.xiy[dir];
    const float* dbl           = sp.dbl[dir];
    const unsigned short* zz   = sp.zb[dir];
    const float* Al            = sp.Al[dir];
    const float* Dpp           = sp.Dp[dir];
    float* cumg                = sp.cumg[dir];
    float* hep                 = sp.he[dir];

    const int by = blockIdx.y;
    const int b = by >> 1, part = by & 1;
    const int rbase = b * LSEQ + part * (LSEQ / 2);
    const int d0 = blockIdx.x << 5;
    const int tid = threadIdx.x;
    const int wave = tid >> 6, lane = tid & 63;
    const int l15 = lane & 15, l4 = lane >> 4;
    const int di = tid >> 3, np = tid & 7;     // inner-loop mapping
    const int lr = tid >> 2, lc = tid & 3;     // stage/epilogue mapping
    const bool lead = (np == 0);

    // A constants pre-scaled by log2(e) so exp2 needs no extra mul
    const f32x2 ALv = {-expf(Al[(d0 + di) * 16 + np]) * 1.4426950408889634f,
                       -expf(Al[(d0 + di) * 16 + np + 8]) * 1.4426950408889634f};

    // dt MFMA B-fragments: rows = the block's 32 channels (two 16-ch halves)
    const short8 dtwf0 = *(const short8*)&dtw[(size_t)(d0 + l15) * 32 + l4 * 8];
    const short8 dtwf1 = *(const short8*)&dtw[(size_t)(d0 + 16 + l15) * 32 + l4 * 8];
    const float dtb0 = dtb[d0 + l15], dtb1 = dtb[d0 + 16 + l15];

    float dpv[8];
#pragma unroll
    for (int i = 0; i < 8; ++i) dpv[i] = Dpp[d0 + lc * 8 + i];

    ushort4 pxi0, pxi1;
    float4 pB, pC;
    short8 pA;
    auto issue_loads = [&](int c) {
        const size_t r = (size_t)rbase + c * 64 + lr;
        pxi0 = *(const ushort4*)&xiy[r * 1024 + d0 + lc * 8];
        pxi1 = *(const ushort4*)&xiy[r * 1024 + d0 + lc * 8 + 4];
        pB   = *(const float4*)&dbl[r * 64 + 32 + lc * 4];
        pC   = *(const float4*)&dbl[r * 64 + 48 + lc * 4];
        // dt MFMA A-fragment: rows = this wave's 16 timesteps of the chunk
        pA   = *(const short8*)&dblh[(size_t)(rbase + c * 64 + wave * 16 + l15) * 32 + l4 * 8];
    };
    issue_loads(0);

    constexpr int NT = (LSEQ / 2) / 64;   // 16 chunks per partition
    f32x2 h = {0.f, 0.f};
    float cum = 0.0f;
    for (int c = 0; c < NT; ++c) {
        const int t0 = c * 64;
        // ---- stage xi raw bf16 [t][ch] and B/C pairs ----
        *(ushort4*)&sxi[lr][lc * 8]     = pxi0;
        *(ushort4*)&sxi[lr][lc * 8 + 4] = pxi1;
        {
            const float bv[4] = {pB.x, pB.y, pB.z, pB.w};
            const float cv[4] = {pC.x, pC.y, pC.z, pC.w};
#pragma unroll
            for (int i = 0; i < 4; ++i) {
                const int n = lc * 4 + i;
                sB2[n & 7][lr * 2 + (n >> 3)] = bv[i];
                sC2[n & 7][lr * 2 + (n >> 3)] = cv[i];
            }
        }
        if (part) __syncthreads();   // guards epilogue(c-1) cum reads on sdt alias
        // ---- dt phase: MFMA -> softplus -> sdt, and dtx = dt*xi -> sdtx ----
        // (sxi reads are intra-wave: rows wave*16..+15 written by this wave)
        {
            f32x4 z4 = {0.f, 0.f, 0.f, 0.f};
            f32x4 dacc0 = __builtin_amdgcn_mfma_f32_16x16x32_bf16(pA, dtwf0, z4, 0, 0, 0);
            f32x4 dacc1 = __builtin_amdgcn_mfma_f32_16x16x32_bf16(pA, dtwf1, z4, 0, 0, 0);
            const int tq = wave * 16 + l4 * 4;
            float4 xi0, xi1;
            xi0.x = bf2f(sxi[tq + 0][l15]);      xi0.y = bf2f(sxi[tq + 1][l15]);
            xi0.z = bf2f(sxi[tq + 2][l15]);      xi0.w = bf2f(sxi[tq + 3][l15]);
            xi1.x = bf2f(sxi[tq + 0][16 + l15]); xi1.y = bf2f(sxi[tq + 1][16 + l15]);
            xi1.z = bf2f(sxi[tq + 2][16 + l15]); xi1.w = bf2f(sxi[tq + 3][16 + l15]);
            float4 dv0, dv1, dx0, dx1;
            dv0.x = softplus_f(dacc0[0] + dtb0); dv0.y = softplus_f(dacc0[1] + dtb0);
            dv0.z = softplus_f(dacc0[2] + dtb0); dv0.w = softplus_f(dacc0[3] + dtb0);
            dv1.x = softplus_f(dacc1[0] + dtb1); dv1.y = softplus_f(dacc1[1] + dtb1);
            dv1.z = softplus_f(dacc1[2] + dtb1); dv1.w = softplus_f(dacc1[3] + dtb1);
            dx0.x = dv0.x * xi0.x; dx0.y = dv0.y * xi0.y;
            dx0.z = dv0.z * xi0.z; dx0.w = dv0.w * xi0.w;
            dx1.x = dv1.x * xi1.x; dx1.y = dv1.y * xi1.y;
            dx1.z = dv1.z * xi1.z; dx1.w = dv1.w * xi1.w;
            *(float4*)&sdt[l15][tq]       = dv0;
            *(float4*)&sdt[16 + l15][tq]  = dv1;
            *(float4*)&sdtx[l15][tq]      = dx0;
            *(float4*)&sdtx[16 + l15][tq] = dx1;
        }
        const ushort4 oxi0 = pxi0, oxi1 = pxi1;
        ushort4 pz0 = {}, pz1 = {};
        if (part == 0) {
            const int tg = t0 + lr;
            const int tz = dir ? (LSEQ - 1 - tg) : tg;
            pz0 = *(const ushort4*)&zz[((size_t)b * LSEQ + tz) * 1024 + d0 + lc * 8];
            pz1 = *(const ushort4*)&zz[((size_t)b * LSEQ + tz) * 1024 + d0 + lc * 8 + 4];
        }
        if (c + 1 < NT) issue_loads(c + 1);
        __syncthreads();   // barC: sdt/sdtx/sB2/sC2 visible, inner may start
        // ---- inner scan: 64 timesteps, 2 states per thread (f32x2 packed) ----
#pragma unroll 4
        for (int tt = 0; tt < 64; tt += 4) {
            const float4 d4 = *(const float4*)&sdt[di][tt];
            const float4 u4 = *(const float4*)&sdtx[di][tt];
            const float4 bA = *(const float4*)&sB2[np][tt * 2];
            const float4 bB = *(const float4*)&sB2[np][tt * 2 + 4];
            const float4 cA = *(const float4*)&sC2[np][tt * 2];
            const float4 cB = *(const float4*)&sC2[np][tt * 2 + 4];
            float4 ppv;
            {
                f32x2 e = ALv * d4.x;
                e.x = EXP2F(e.x); e.y = EXP2F(e.y);
                const f32x2 b2 = {bA.x, bA.y};
                const f32x2 c2 = {cA.x, cA.y};
                h = e * h + b2 * u4.x;
                const f32x2 pc = h * c2;
                ppv.x = row_sum8(pc.x + pc.y);
            }
            {
                f32x2 e = ALv * d4.y;
                e.x = EXP2F(e.x); e.y = EXP2F(e.y);
                const f32x2 b2 = {bA.z, bA.w};
                const f32x2 c2 = {cA.z, cA.w};
                h = e * h + b2 * u4.y;
                const f32x2 pc = h * c2;
                ppv.y = row_sum8(pc.x + pc.y);
            }
            {
                f32x2 e = ALv * d4.z;
                e.x = EXP2F(e.x); e.y = EXP2F(e.y);
                const f32x2 b2 = {bB.x, bB.y};
                const f32x2 c2 = {cB.x, cB.y};
                h = e * h + b2 * u4.z;
                const f32x2 pc = h * c2;
                ppv.z = row_sum8(pc.x + pc.y);
            }
            {
                f32x2 e = ALv * d4.w;
                e.x = EXP2F(e.x); e.y = EXP2F(e.y);
                const f32x2 b2 = {bB.z, bB.w};
                const f32x2 c2 = {cB.z, cB.w};
                h = e * h + b2 * u4.w;
                const f32x2 pc = h * c2;
                ppv.w = row_sum8(pc.x + pc.y);
            }
            if (part) {
                const float c0 = cum + d4.x, c1 = c0 + d4.y;
                const float c2s = c1 + d4.z, c3 = c2s + d4.w;
                cum = c3;
                if (lead) {
                    float4 cc; cc.x = c0; cc.y = c1; cc.z = c2s; cc.w = c3;
                    *(float4*)&sdt[di][tt] = cc;    // scum alias (own row, intra-wave)
                }
            }
            if (lead) *(float4*)&sy[di][tt] = ppv;
        }
        __syncthreads();   // barD: sy/scum complete; staging arrays free
        // ---- epilogue ----
        if (part == 0) {
            const size_t r = (size_t)rbase + t0 + lr;
            ushort4 s0, s1;
            s0.x = f2bf(fmaf(bf2f(oxi0.x), dpv[0], sy[lc * 8 + 0][lr]) * silu_f(bf2f(pz0.x)));
            s0.y = f2bf(fmaf(bf2f(oxi0.y), dpv[1], sy[lc * 8 + 1][lr]) * silu_f(bf2f(pz0.y)));
            s0.z = f2bf(fmaf(bf2f(oxi0.z), dpv[2], sy[lc * 8 + 2][lr]) * silu_f(bf2f(pz0.z)));
            s0.w = f2bf(fmaf(bf2f(oxi0.w), dpv[3], sy[lc * 8 + 3][lr]) * silu_f(bf2f(pz0.w)));
            s1.x = f2bf(fmaf(bf2f(oxi1.x), dpv[4], sy[lc * 8 + 4][lr]) * silu_f(bf2f(pz1.x)));
            s1.y = f2bf(fmaf(bf2f(oxi1.y), dpv[5], sy[lc * 8 + 5][lr]) * silu_f(bf2f(pz1.y)));
            s1.z = f2bf(fmaf(bf2f(oxi1.z), dpv[6], sy[lc * 8 + 6][lr]) * silu_f(bf2f(pz1.z)));
            s1.w = f2bf(fmaf(bf2f(oxi1.w), dpv[7], sy[lc * 8 + 7][lr]) * silu_f(bf2f(pz1.w)));
            *(ushort4*)&xiy[r * 1024 + d0 + lc * 8] = s0;
            *(ushort4*)&xiy[r * 1024 + d0 + lc * 8 + 4] = s1;
        } else {
            // raw y + xi*Dp as bf16 in place; cum coalesced f32
            const size_t r = (size_t)rbase + t0 + lr;
            ushort4 s0, s1;
            s0.x = f2bf(fmaf(bf2f(oxi0.x), dpv[0], sy[lc * 8 + 0][lr]));
            s0.y = f2bf(fmaf(bf2f(oxi0.y), dpv[1], sy[lc * 8 + 1][lr]));
            s0.z = f2bf(fmaf(bf2f(oxi0.z), dpv[2], sy[lc * 8 + 2][lr]));
            s0.w = f2bf(fmaf(bf2f(oxi0.w), dpv[3], sy[lc * 8 + 3][lr]));
            s1.x = f2bf(fmaf(bf2f(oxi1.x), dpv[4], sy[lc * 8 + 4][lr]));
            s1.y = f2bf(fmaf(bf2f(oxi1.y), dpv[5], sy[lc * 8 + 5][lr]));
            s1.z = f2bf(fmaf(bf2f(oxi1.z), dpv[6], sy[lc * 8 + 6][lr]));
            s1.w = f2bf(fmaf(bf2f(oxi1.w), dpv[7], sy[lc * 8 + 7][lr]));
            *(ushort4*)&xiy[r * 1024 + d0 + lc * 8] = s0;
            *(ushort4*)&xiy[r * 1024 + d0 + lc * 8 + 4] = s1;
            float4 c0v, c1v;
            c0v.x = sdt[lc * 8 + 0][lr]; c0v.y = sdt[lc * 8 + 1][lr];
            c0v.z = sdt[lc * 8 + 2][lr]; c0v.w = sdt[lc * 8 + 3][lr];
            c1v.x = sdt[lc * 8 + 4][lr]; c1v.y = sdt[lc * 8 + 5][lr];
            c1v.z = sdt[lc * 8 + 6][lr]; c1v.w = sdt[lc * 8 + 7][lr];
            const size_t pr = (size_t)(b * (LSEQ / 2) + t0 + lr) * 1024 + d0 + lc * 8;
            *(float4*)&cumg[pr]     = c0v;
            *(float4*)&cumg[pr + 4] = c1v;
        }
    }
    if (part == 0) {
        float* hh = &hep[((size_t)b * 1024 + d0 + di) * 16 + np];
        hh[0] = h.x; hh[8] = h.y;
    }
}

// ---------------------------------------------------------------------------
// Part-1 fixup: block = 32 ch x 256 t-quarter x batch; AL/HE/C staged ONCE
// in LDS. Round 7: 2 channels per thread (float2/ushort2), 16 iters of 16 t.
// ---------------------------------------------------------------------------
struct FixArgs {
    const float* cumg[2]; const float* he[2]; const float* al2[2];
    const float* dbl[2];  const unsigned short* zb[2]; unsigned short* xiy[2];
};
__global__ __launch_bounds__(256) void fix_k(FixArgs a)
{
    const int dir = blockIdx.z;
    const float* cumg          = a.cumg[dir];
    const float* he            = a.he[dir];
    const float* al2           = a.al2[dir];
    const float* dbl           = a.dbl[dir];
    const unsigned short* zz   = a.zb[dir];
    unsigned short* xiy        = a.xiy[dir];

    __shared__ float sAL[32][17], sHE[32][17];
    __shared__ float sCt[256][16];

    const int tid = threadIdx.x;
    const int d0 = blockIdx.x << 5;           // 32-ch block
    const int by = blockIdx.y;
    const int b = by >> 2, q = by & 3;        // quarter (256 t) of part 1
    const int tq0 = q << 8;

    for (int i = tid; i < 512; i += 256) {
        const int dd = i >> 4, nn = i & 15;
        sAL[dd][nn] = al2[(size_t)(d0 + dd) * 16 + nn];
        sHE[dd][nn] = he[((size_t)b * 1024 + d0 + dd) * 16 + nn];
    }
    for (int i = tid; i < 4096; i += 256) {
        const int tt = i >> 4, nn = i & 15;
        sCt[tt][nn] = dbl[((size_t)b * LSEQ + (LSEQ / 2) + tq0 + tt) * 64 + 48 + nn];
    }
    __syncthreads();

    const int ts = tid >> 4, dd = (tid & 15) * 2;   // 16 t-rows x 16 ch-pairs
    for (int it = 0; it < 16; ++it) {
        const int tloc = it * 16 + ts;                // t within quarter
        const int tl = tq0 + tloc;                    // part-local t
        const int tglob = (LSEQ / 2) + tl;
        const size_t grow = (size_t)b * LSEQ + tglob;
        const float2 cv = *(const float2*)&cumg[((size_t)b * (LSEQ / 2) + tl) * 1024 + d0 + dd];
        const ushort2 yv = *(const ushort2*)&xiy[grow * 1024 + d0 + dd];
        const int tz = dir ? (LSEQ - 1 - tglob) : tglob;
        const ushort2 zv = *(const ushort2*)&zz[((size_t)b * LSEQ + tz) * 1024 + d0 + dd];
        float corr0 = 0.f, corr1 = 0.f;
#pragma unroll
        for (int n = 0; n < 16; ++n) {
            const float ct = sCt[tloc][n];
            corr0 = fmaf(ct * sHE[dd + 0][n], EXP2F(sAL[dd + 0][n] * cv.x), corr0);
            corr1 = fmaf(ct * sHE[dd + 1][n], EXP2F(sAL[dd + 1][n] * cv.y), corr1);
        }
        ushort2 o;
        o.x = f2bf((bf2f(yv.x) + corr0) * silu_f(bf2f(zv.x)));
        o.y = f2bf((bf2f(yv.y) + corr1) * silu_f(bf2f(zv.y)));
        *(ushort2*)&xiy[grow * 1024 + d0 + dd] = o;
    }
}

// ---------------------------------------------------------------------------
extern "C" void kernel_launch(void* const* d_in, const int* in_sizes, int n_in,
                              void* d_out, int out_size, void* d_ws, size_t ws_size,
                              hipStream_t stream)
{
    const float* x      = (const float*)d_in[0];
    const float* f_in_w = (const float*)d_in[1];
    const float* f_cw   = (const float*)d_in[2];
    const float* f_cb   = (const float*)d_in[3];
    const float* f_xp   = (const float*)d_in[4];
    const float* f_dtw  = (const float*)d_in[5];
    const float* f_dtb  = (const float*)d_in[6];
    const float* f_Al   = (const float*)d_in[7];
    const float* f_Dp   = (const float*)d_in[8];
    const float* f_ow   = (const float*)d_in[9];
    const float* b_in_w = (const float*)d_in[10];
    const float* b_cw   = (const float*)d_in[11];
    const float* b_cb   = (const float*)d_in[12];
    const float* b_xp   = (const float*)d_in[13];
    const float* b_dtw  = (const float*)d_in[14];
    const float* b_dtb  = (const float*)d_in[15];
    const float* b_Al   = (const float*)d_in[16];
    const float* b_Dp   = (const float*)d_in[17];
    const float* b_ow   = (const float*)d_in[18];
    const float* lin_w  = (const float*)d_in[19];
    const float* lin_b  = (const float*)d_in[20];
    float* out = (float*)d_out;

    char* p = (char*)d_ws;
    auto take = [&](size_t bytes) -> char* {
        char* r = p; p += (bytes + 255) & ~(size_t)255; return r;
    };

    // persistent bf16 weights + AL2 tables
    unsigned short* wif  = (unsigned short*)take((size_t)2048 * 512 * 2);
    unsigned short* wib  = (unsigned short*)take((size_t)2048 * 512 * 2);
    unsigned short* wxf  = (unsigned short*)take((size_t)64 * 1024 * 2);
    unsigned short* wxb  = (unsigned short*)take((size_t)64 * 1024 * 2);
    unsigned short* wdtf = (unsigned short*)take((size_t)1024 * 32 * 2);
    unsigned short* wdtb = (unsigned short*)take((size_t)1024 * 32 * 2);
    unsigned short* wcmb = (unsigned short*)take((size_t)512 * 2048 * 2);
    float* al2f = (float*)take((size_t)1024 * 16 * 4);
    float* al2b = (float*)take((size_t)1024 * 16 * 4);

    const size_t used = (size_t)(p - (char*)d_ws);
    // per-row bytes: xbf 1024 + per dir (xc 2048 + zb 2048 + xiy 2048 + dbl 256
    //                                    + dblh 64); cum ALIASED onto xc.
    const size_t perRow = 1024 + 2 * (2048 + 2048 + 2048 + 256 + 64);
    int G = 1;
    for (int g = 8; g >= 1; g >>= 1) {
        const size_t need = used + (size_t)g * LSEQ * perRow + (size_t)g * 2 * 1024 * 16 * 4 + 16384;
        if (need <= ws_size || g == 1) { G = g; break; }
    }

    CvtArgs ca;
    ca.s[0] = f_in_w; ca.d[0] = wif;  ca.n[0] = 2048 * 512;
    ca.s[1] = b_in_w; ca.d[1] = wib;  ca.n[1] = 2048 * 512;
    ca.s[2] = f_xp;   ca.d[2] = wxf;  ca.n[2] = 64 * 1024;
    ca.s[3] = b_xp;   ca.d[3] = wxb;  ca.n[3] = 64 * 1024;
    ca.s[4] = f_dtw;  ca.d[4] = wdtf; ca.n[4] = 1024 * 32;
    ca.s[5] = b_dtw;  ca.d[5] = wdtb; ca.n[5] = 1024 * 32;
    cvt_k<<<dim3(128, 6), 256, 0, stream>>>(ca);

    alprep_k<<<dim3(64), 256, 0, stream>>>(f_Al, b_Al, al2f, al2b);

    // combined (lin_w @ out_w) weight, bf16, (512 x 2048) — proven r7
    combine_k<<<dim3(4, 128, 2), 256, 0, stream>>>(lin_w, f_ow, b_ow, wcmb);

    char* pg0 = p;
    for (int g0 = 0; g0 < NBATCH; g0 += G) {
        const int Mg = G * LSEQ;
        p = pg0;
        unsigned short* xbf   = (unsigned short*)take((size_t)Mg * 512 * 2);
        unsigned short* xc_f  = (unsigned short*)take((size_t)Mg * 1024 * 2);
        unsigned short* zb_f  = (unsigned short*)take((size_t)Mg * 1024 * 2);
        unsigned short* xc_b  = (unsigned short*)take((size_t)Mg * 1024 * 2);
        unsigned short* zb_b  = (unsigned short*)take((size_t)Mg * 1024 * 2);
        unsigned short* xiy_f = (unsigned short*)take((size_t)Mg * 1024 * 2);
        unsigned short* xiy_b = (unsigned short*)take((size_t)Mg * 1024 * 2);
        float* dbl_f          = (float*)take((size_t)Mg * 64 * 4);
        float* dbl_b          = (float*)take((size_t)Mg * 64 * 4);
        unsigned short* dblh_f= (unsigned short*)take((size_t)Mg * 32 * 2);
        unsigned short* dblh_b= (unsigned short*)take((size_t)Mg * 32 * 2);
        float* he_f           = (float*)take((size_t)G * 1024 * 16 * 4);
        float* he_b           = (float*)take((size_t)G * 1024 * 16 * 4);
        // cum aliased onto dead conv-input buffers (exact size match)
        float* cum_f = (float*)xc_f;
        float* cum_b = (float*)xc_b;

        const float* xg = x + (size_t)g0 * LSEQ * 512;
        float* outg = out + (size_t)g0 * LSEQ * 512;

        cvtx_k<<<dim3(512), 256, 0, stream>>>(xg, xbf, Mg * 512 / 4);

        GemmPair g1 = {};   // in-proj: split output xc (cols<1024) / zb (>=1024)
        g1.A[0] = xbf; g1.A[1] = xbf; g1.W[0] = wif; g1.W[1] = wib;
        g1.C[0] = xc_f; g1.C[1] = xc_b; g1.Cz[0] = zb_f; g1.Cz[1] = zb_b;
        gemm_mfma<2,2,1,0,0,1><<<dim3(Mg/128, 16, 2), 256, 0, stream>>>(g1, 512, 512, 1024, 512);

        conv_silu_k<<<dim3(Mg/8, 2), 256, 0, stream>>>(xc_f, f_cw, f_cb, xiy_f,
                                                       xc_b, b_cw, b_cb, xiy_b);

        GemmPair g2 = {};   // x-proj: dbl f32 (ldc 64) + bf16 cols<32 (dblh)
        g2.A[0] = xiy_f; g2.A[1] = xiy_b; g2.W[0] = wxf; g2.W[1] = wxb;
        g2.C[0] = dbl_f; g2.C[1] = dbl_b; g2.aux[0] = dblh_f; g2.aux[1] = dblh_b;
        gemm_mfma<2,1,0,0,1><<<dim3(Mg/128, 1, 2), 128, 0, stream>>>(g2, 1024, 1024, 64, 1024);

        ScanPair spp = {};  // scan: seq-split P=2, 1024 rows per block
        spp.dblh[0] = dblh_f; spp.dblh[1] = dblh_b;
        spp.dtw[0] = wdtf;    spp.dtw[1] = wdtb;
        spp.dtb[0] = f_dtb;   spp.dtb[1] = b_dtb;
        spp.xiy[0] = xiy_f;   spp.xiy[1] = xiy_b;
        spp.dbl[0] = dbl_f;   spp.dbl[1] = dbl_b;
        spp.zb[0] = zb_f;     spp.zb[1] = zb_b;
        spp.Al[0] = f_Al;     spp.Al[1] = b_Al;
        spp.Dp[0] = f_Dp;     spp.Dp[1] = b_Dp;
        spp.cumg[0] = cum_f;  spp.cumg[1] = cum_b;
        spp.he[0] = he_f;     spp.he[1] = he_b;
        scan_k<<<dim3(32, G * 2, 2), 256, 0, stream>>>(spp);

        FixArgs fa = {};
        fa.cumg[0] = cum_f; fa.cumg[1] = cum_b;
        fa.he[0] = he_f;    fa.he[1] = he_b;
        fa.al2[0] = al2f;   fa.al2[1] = al2b;
        fa.dbl[0] = dbl_f;  fa.dbl[1] = dbl_b;
        fa.zb[0] = zb_f;    fa.zb[1] = zb_b;
        fa.xiy[0] = xiy_f;  fa.xiy[1] = xiy_b;
        fix_k<<<dim3(32, G * 4, 2), 256, 0, stream>>>(fa);

        // fused out-proj+final: out = [y_f | rev(y_b)] @ Wcomb^T + lin_b (K=2048)
        GemmPair g5 = {};
        g5.A[0] = xiy_f; g5.A2[0] = xiy_b; g5.W[0] = wcmb;
        g5.bias[0] = lin_b; g5.C[0] = outg;
        gemm_mfma<2,2,0,1024,0><<<dim3(Mg/128, 4, 1), 256, 0, stream>>>(g5, 1024, 2048, 512, 2048);
    }
}